// Round 2
// baseline (3491.524 us; speedup 1.0000x reference)
//
#include <hip/hip_runtime.h>
#include <math.h>

namespace {

constexpr int Bb = 256, Tt = 512, Dp = 256, Hh = 128, G = 512;
constexpr int M = Tt * Bb; // 131072 rows (t-major: row = t*B + b)

__device__ __forceinline__ float sigf(float x) { return 1.0f / (1.0f + __expf(-x)); }
__device__ __forceinline__ float tanhfast(float x) {
  x = fminf(15.0f, fmaxf(-15.0f, x));
  float e = __expf(2.0f * x);
  return (e - 1.0f) / (e + 1.0f);
}
__device__ __forceinline__ float b2f(unsigned short u) {
  return __uint_as_float((unsigned int)u << 16);
}
__device__ __forceinline__ unsigned short f2b(float f) {
  unsigned int u = __float_as_uint(f);
  u += 0x7FFFu + ((u >> 16) & 1u);   // round-to-nearest-even
  return (unsigned short)(u >> 16);
}

// C[m][n] = sum_k A[arow(m)][k] * W[n][k] + bias1[n] (+bias2[n]); optional tanh.
// A: fp32 or bf16 (ushort). C: fp32 or bf16. W/bias: fp32.
// Tiles: 32 rows x 128 cols per block, K staged in 64-chunks in LDS (fp32).
template<int K, int SWAP, int TANH, typename AT, typename CT>
__global__ __launch_bounds__(256) void gemm_k(const AT* __restrict__ A,
    const float* __restrict__ W, const float* __restrict__ bias1,
    const float* __restrict__ bias2, CT* __restrict__ C, int N) {
  __shared__ float As[32 * 68];   // stride 68 (keeps float4 alignment, spreads banks)
  __shared__ float Ws[128 * 68];
  const int tid = threadIdx.x;
  const int m0 = blockIdx.x * 32;
  const int n0 = blockIdx.y * 128;
  const int c0 = tid & 31;
  const int i0 = (tid >> 5) << 2;
  float acc[4][4] = {};
  for (int kc = 0; kc < K; kc += 64) {
    if constexpr (sizeof(AT) == 4) {  // fp32 A (optionally B,T-swapped source)
      int idx = tid;
#pragma unroll
      for (int q = 0; q < 2; ++q) {
        int row = idx >> 4, kq = idx & 15;
        int m = m0 + row;
        int ar = SWAP ? ((m & 255) * Tt + (m >> 8)) : m;  // x is [B][T][...]
        const float4 v = *reinterpret_cast<const float4*>(
            reinterpret_cast<const float*>(A) + (size_t)ar * K + kc + kq * 4);
        *reinterpret_cast<float4*>(&As[row * 68 + kq * 4]) = v;
        idx += 256;
      }
    } else {  // bf16 A: 32x64 tile = 2048 elems, 8 per thread
      const int row = tid >> 3, g8 = (tid & 7) * 8;
      const unsigned short* src =
          reinterpret_cast<const unsigned short*>(A) + (size_t)(m0 + row) * K + kc + g8;
      const uint4 v = *reinterpret_cast<const uint4*>(src);
      float f[8];
      f[0] = b2f((unsigned short)(v.x & 0xFFFF)); f[1] = b2f((unsigned short)(v.x >> 16));
      f[2] = b2f((unsigned short)(v.y & 0xFFFF)); f[3] = b2f((unsigned short)(v.y >> 16));
      f[4] = b2f((unsigned short)(v.z & 0xFFFF)); f[5] = b2f((unsigned short)(v.z >> 16));
      f[6] = b2f((unsigned short)(v.w & 0xFFFF)); f[7] = b2f((unsigned short)(v.w >> 16));
      *reinterpret_cast<float4*>(&As[row * 68 + g8]) = make_float4(f[0], f[1], f[2], f[3]);
      *reinterpret_cast<float4*>(&As[row * 68 + g8 + 4]) = make_float4(f[4], f[5], f[6], f[7]);
    }
    {
      int idx = tid;
#pragma unroll
      for (int q = 0; q < 8; ++q) {
        int row = idx >> 4, kq = idx & 15;
        const float4 v = *reinterpret_cast<const float4*>(W + (size_t)(n0 + row) * K + kc + kq * 4);
        *reinterpret_cast<float4*>(&Ws[row * 68 + kq * 4]) = v;
        idx += 256;
      }
    }
    __syncthreads();
#pragma unroll
    for (int k4 = 0; k4 < 16; ++k4) {
      float4 a4[4], w4[4];
#pragma unroll
      for (int i = 0; i < 4; ++i)
        a4[i] = *reinterpret_cast<const float4*>(&As[(i0 + i) * 68 + k4 * 4]);
#pragma unroll
      for (int j = 0; j < 4; ++j)
        w4[j] = *reinterpret_cast<const float4*>(&Ws[(c0 + 32 * j) * 68 + k4 * 4]);
#pragma unroll
      for (int i = 0; i < 4; ++i)
#pragma unroll
        for (int j = 0; j < 4; ++j) {
          acc[i][j] += a4[i].x * w4[j].x;
          acc[i][j] += a4[i].y * w4[j].y;
          acc[i][j] += a4[i].z * w4[j].z;
          acc[i][j] += a4[i].w * w4[j].w;
        }
    }
    __syncthreads();
  }
#pragma unroll
  for (int j = 0; j < 4; ++j) {
    const int col = n0 + c0 + 32 * j;
    float bbv = bias1 ? bias1[col] : 0.0f;
    if (bias2) bbv += bias2[col];
#pragma unroll
    for (int i = 0; i < 4; ++i) {
      float v = acc[i][j] + bbv;
      if (TANH) v = tanhfast(v);
      const size_t oidx = (size_t)(m0 + i0 + i) * N + col;
      if constexpr (sizeof(CT) == 2) C[oidx] = f2b(v); else C[oidx] = v;
    }
  }
}

// Bidirectional chunked LSTM. One block = one direction x 2 batch rows.
// Thread j holds W_hh[j][0:128] (fp32) in VGPRs; h broadcast via LDS.
// P (pre-gates) and Y are bf16; state h/c fp32. grid 256, block 512.
__global__ __launch_bounds__(512, 2) void lstm_k(const unsigned short* __restrict__ P,
    const float* __restrict__ Whh, const float* __restrict__ wtime,
    unsigned short* __restrict__ Y) {
  const int tid = threadIdx.x;
  const int dir = blockIdx.x >> 7;
  const int b0 = (blockIdx.x & 127) * 2;
  __shared__ float hbuf[2 * 128];
  __shared__ float gbuf[2 * 512];
  __shared__ float wts[32];
  float w[128];
#pragma unroll
  for (int k4 = 0; k4 < 32; ++k4) {
    const float4 v = *reinterpret_cast<const float4*>(Whh + (size_t)tid * 128 + k4 * 4);
    w[k4 * 4 + 0] = v.x; w[k4 * 4 + 1] = v.y; w[k4 * 4 + 2] = v.z; w[k4 * 4 + 3] = v.w;
  }
  if (tid < 32) wts[tid] = wtime[tid];
  if (tid < 256) hbuf[tid] = 0.0f;
  const int bown = tid >> 7, u = tid & 127;  // valid when tid<256
  float c = 0.f, hacc = 0.f, cacc = 0.f;
  __syncthreads();
  const int trow0 = dir ? (Tt - 1) : 0;
  float pg0 = b2f(P[((size_t)trow0 * Bb + b0) * G + tid]);
  float pg1 = b2f(P[((size_t)trow0 * Bb + b0 + 1) * G + tid]);
  for (int s = 0; s < Tt; ++s) {
    float npg0 = 0.f, npg1 = 0.f;
    if (s + 1 < Tt) {  // prefetch next step's pre-gates
      const int trn = dir ? (Tt - 2 - s) : (s + 1);
      npg0 = b2f(P[((size_t)trn * Bb + b0) * G + tid]);
      npg1 = b2f(P[((size_t)trn * Bb + b0 + 1) * G + tid]);
    }
    float acc0 = pg0, acc1 = pg1;
#pragma unroll
    for (int k4 = 0; k4 < 32; ++k4) {
      const float4 h0 = *reinterpret_cast<const float4*>(&hbuf[k4 * 4]);
      const float4 h1 = *reinterpret_cast<const float4*>(&hbuf[128 + k4 * 4]);
      acc0 += w[k4*4+0]*h0.x + w[k4*4+1]*h0.y + w[k4*4+2]*h0.z + w[k4*4+3]*h0.w;
      acc1 += w[k4*4+0]*h1.x + w[k4*4+1]*h1.y + w[k4*4+2]*h1.z + w[k4*4+3]*h1.w;
    }
    gbuf[tid] = acc0;
    gbuf[512 + tid] = acc1;
    __syncthreads();
    if (tid < 256) {
      const float gi = gbuf[bown * 512 + u];
      const float gf = gbuf[bown * 512 + 128 + u];
      const float gg = gbuf[bown * 512 + 256 + u];
      const float go = gbuf[bown * 512 + 384 + u];
      c = sigf(gf) * c + sigf(gi) * tanhfast(gg);
      float hn = sigf(go) * tanhfast(c);
      const int sin = s & 31;
      const float wt = wts[sin];
      hacc += wt * hn;   // online time-reweighting accumulation
      cacc += wt * c;
      if (sin == 31) { hn = hacc; c = cacc; hacc = 0.f; cacc = 0.f; }
      hbuf[bown * 128 + u] = hn;
      Y[((size_t)s * Bb + b0 + bown) * Dp + dir * Hh + u] = f2b(hn);
    }
    __syncthreads();
    pg0 = npg0; pg1 = npg1;
  }
}

// pot[m][r] = tmp[m][:] . W_a2[r][:]   (tmp fp32)
__global__ __launch_bounds__(256) void pot_k(const float* __restrict__ tmp,
    const float* __restrict__ Wa2, float* __restrict__ pot) {
  const int tid = threadIdx.x;
  const int row = blockIdx.x * 32 + (tid >> 3);
  const int r = tid & 7;
  __shared__ float w2[8 * 129];
  for (int i = tid; i < 1024; i += 256) w2[(i >> 7) * 129 + (i & 127)] = Wa2[i];
  __syncthreads();
  float acc = 0.f;
  const float* tr = tmp + (size_t)row * 128;
#pragma unroll
  for (int k4 = 0; k4 < 32; ++k4) {
    const float4 tv = *reinterpret_cast<const float4*>(tr + k4 * 4);
    acc += tv.x * w2[r * 129 + k4 * 4 + 0];
    acc += tv.y * w2[r * 129 + k4 * 4 + 1];
    acc += tv.z * w2[r * 129 + k4 * 4 + 2];
    acc += tv.w * w2[r * 129 + k4 * 4 + 3];
  }
  pot[(size_t)row * 8 + r] = acc;
}

// masked softmax over t for one (b,r); writes Wt[b][r][t]
__global__ __launch_bounds__(256) void softmax_k(const float* __restrict__ pot,
    const int* __restrict__ length, float* __restrict__ Wt) {
  const int b = blockIdx.x >> 3, r = blockIdx.x & 7;
  const int tid = threadIdx.x;
  const int len = length[b];
  __shared__ float rbuf[4];
  const int t1 = tid, t2 = tid + 256;
  const float x1 = (t1 < len) ? pot[((size_t)t1 * Bb + b) * 8 + r] : -INFINITY;
  const float x2 = (t2 < len) ? pot[((size_t)t2 * Bb + b) * 8 + r] : -INFINITY;
  float m = fmaxf(x1, x2);
#pragma unroll
  for (int off = 32; off >= 1; off >>= 1) m = fmaxf(m, __shfl_xor(m, off));
  if ((tid & 63) == 0) rbuf[tid >> 6] = m;
  __syncthreads();
  m = fmaxf(fmaxf(rbuf[0], rbuf[1]), fmaxf(rbuf[2], rbuf[3]));
  const float e1 = (t1 < len) ? __expf(x1 - m) : 0.f;
  const float e2 = (t2 < len) ? __expf(x2 - m) : 0.f;
  float ssum = e1 + e2;
#pragma unroll
  for (int off = 32; off >= 1; off >>= 1) ssum += __shfl_xor(ssum, off);
  __syncthreads();
  if ((tid & 63) == 0) rbuf[tid >> 6] = ssum;
  __syncthreads();
  ssum = rbuf[0] + rbuf[1] + rbuf[2] + rbuf[3];
  const float inv = 1.0f / ssum;
  float* wrow = Wt + ((size_t)b * 8 + r) * Tt;
  wrow[t1] = e1 * inv;
  wrow[t2] = e2 * inv;
}

// Per-b: pooled = sum_t w[r][t]*Y[t][b][:], logits, log_softmax, gram penalty.
__global__ __launch_bounds__(256) void pool_k(const unsigned short* __restrict__ Y,
    const float* __restrict__ Wt, const float* __restrict__ Wout,
    const float* __restrict__ bout, float* __restrict__ outF,
    float* __restrict__ penpart) {
  const int b = blockIdx.x;
  const int tid = threadIdx.x;
  __shared__ float ws[8 * 513];
  __shared__ float pooled[2048];
  __shared__ float red[256];
  __shared__ float lg[8];
  for (int i = tid; i < 4096; i += 256) ws[(i >> 9) * 513 + (i & 511)] = Wt[(size_t)b * 4096 + i];
  __syncthreads();
  float acc[8] = {};
  for (int t = 0; t < Tt; ++t) {
    const float y = b2f(Y[((size_t)t * Bb + b) * Dp + tid]);
#pragma unroll
    for (int r = 0; r < 8; ++r) acc[r] += ws[r * 513 + t] * y;
  }
#pragma unroll
  for (int r = 0; r < 8; ++r) pooled[r * 256 + tid] = acc[r];
  __syncthreads();
  for (int o = 0; o < 7; ++o) {
    float p = 0.f;
    for (int j = tid; j < 2048; j += 256) p += pooled[j] * Wout[(size_t)o * 2048 + j];
    red[tid] = p;
    __syncthreads();
    for (int st = 128; st >= 1; st >>= 1) {
      if (tid < st) red[tid] += red[tid + st];
      __syncthreads();
    }
    if (tid == 0) lg[o] = red[0] + bout[o];
    __syncthreads();
  }
  if (tid == 0) {
    float mx = lg[0];
    for (int o = 1; o < 7; ++o) mx = fmaxf(mx, lg[o]);
    float ssum = 0.f;
    for (int o = 0; o < 7; ++o) ssum += __expf(lg[o] - mx);
    const float lse = mx + __logf(ssum);
    for (int o = 0; o < 7; ++o) outF[b * 7 + o] = lg[o] - lse;
  }
  for (int i = tid; i < 4096; i += 256) {
    const int rr = i >> 9, t = i & 511;
    ws[rr * 513 + t] = sqrtf(ws[rr * 513 + t]);
  }
  __syncthreads();
  float pp = 0.f;
  if (tid < 64) {
    const int rr = tid >> 3, ssi = tid & 7;
    float g = 0.f;
    for (int t = 0; t < Tt; ++t) g += ws[rr * 513 + t] * ws[ssi * 513 + t];
    const float d = g - 1.0f;
    pp = d * d;
  }
  red[tid] = pp;
  __syncthreads();
  for (int st = 128; st >= 1; st >>= 1) {
    if (tid < st) red[tid] += red[tid + st];
    __syncthreads();
  }
  if (tid == 0) penpart[b] = red[0];
}

__global__ __launch_bounds__(256) void penred_k(const float* __restrict__ penpart,
                                                float* __restrict__ outp) {
  const int tid = threadIdx.x;
  __shared__ float red[256];
  red[tid] = penpart[tid];
  __syncthreads();
  for (int st = 128; st >= 1; st >>= 1) {
    if (tid < st) red[tid] += red[tid + st];
    __syncthreads();
  }
  if (tid == 0) outp[0] = red[0];
}

} // namespace

extern "C" void kernel_launch(void* const* d_in, const int* in_sizes, int n_in,
                              void* d_out, int out_size, void* d_ws, size_t ws_size,
                              hipStream_t stream) {
  (void)in_sizes; (void)n_in; (void)out_size;
  const float* x     = (const float*)d_in[0];
  const float* W_in  = (const float*)d_in[1];
  const float* b_in  = (const float*)d_in[2];
  const float* W_ih  = (const float*)d_in[3];
  const float* b_ih  = (const float*)d_in[4];
  const float* W_hh  = (const float*)d_in[5];
  const float* b_hh  = (const float*)d_in[6];
  const float* wtime = (const float*)d_in[7];
  const float* W_a1  = (const float*)d_in[8];
  const float* b_a1  = (const float*)d_in[9];
  const float* W_a2  = (const float*)d_in[10];
  const float* W_out = (const float*)d_in[11];
  const float* b_out = (const float*)d_in[12];
  const int*   length= (const int*)d_in[13];
  float* outF = (float*)d_out;

  typedef unsigned short bf16;
  char* ws = (char*)d_ws;
  size_t off = 0;
  auto alloc = [&](size_t bytes) {
    void* p = ws + off; off += (bytes + 255) & ~(size_t)255; return p;
  };
  bf16*  act  = (bf16*)alloc((size_t)M * 256 * 2);   // activations [T*B][256], bf16 (64MB)
  bf16*  Pg   = (bf16*)alloc((size_t)M * 512 * 2);   // pre-gates  [T*B][512], bf16 (128MB)
  float* pot  = (float*)alloc((size_t)M * 8 * 4);    // 4MB
  float* Wt   = (float*)alloc((size_t)Bb * 8 * Tt * 4); // 4MB
  float* penp = (float*)alloc(Bb * 4);
  float* tmpA = (float*)Pg;  // attention tanh activations [M][128] fp32, aliases dead Pg

  if (ws_size < off) return;  // workspace too small: clean absmax-fail, not a crash

  const dim3 blk(256);
  // input layer: rows (t,b) <- x[b][t][:]
  gemm_k<128, 1, 0, float, bf16><<<dim3(M / 32, 2), blk, 0, stream>>>(x, W_in, b_in, nullptr, act, 256);
  // layer 0 (lstm overwrites act after the gemm has consumed it)
  gemm_k<256, 0, 0, bf16, bf16><<<dim3(M / 32, 4), blk, 0, stream>>>(act, W_ih, b_ih, b_hh, Pg, 512);
  lstm_k<<<dim3(256), dim3(512), 0, stream>>>(Pg, W_hh, wtime, act);
  // layer 1 (shared weights)
  gemm_k<256, 0, 0, bf16, bf16><<<dim3(M / 32, 4), blk, 0, stream>>>(act, W_ih, b_ih, b_hh, Pg, 512);
  lstm_k<<<dim3(256), dim3(512), 0, stream>>>(Pg, W_hh, wtime, act);
  // attention
  gemm_k<256, 0, 1, bf16, float><<<dim3(M / 32, 1), blk, 0, stream>>>(act, W_a1, b_a1, nullptr, tmpA, 128);
  pot_k<<<dim3(M / 32), blk, 0, stream>>>(tmpA, W_a2, pot);
  softmax_k<<<dim3(Bb * 8), blk, 0, stream>>>(pot, length, Wt);
  pool_k<<<dim3(Bb), blk, 0, stream>>>(act, Wt, W_out, b_out, outF, penp);
  penred_k<<<dim3(1), blk, 0, stream>>>(penp, outF + Bb * 7);
}

// Round 3
// 3152.698 us; speedup vs baseline: 1.1075x; 1.1075x over previous
//
#include <hip/hip_runtime.h>
#include <math.h>

namespace {

constexpr int Bb = 256, Tt = 512, Dp = 256, Hh = 128, G = 512;
constexpr int M = Tt * Bb; // 131072 rows (t-major: row = t*B + b)

typedef __attribute__((ext_vector_type(8))) short short8v;
typedef __attribute__((ext_vector_type(4))) float f32x4;

__device__ __forceinline__ float sigf(float x) { return 1.0f / (1.0f + __expf(-x)); }
__device__ __forceinline__ float tanhfast(float x) {
  x = fminf(15.0f, fmaxf(-15.0f, x));
  float e = __expf(2.0f * x);
  return (e - 1.0f) / (e + 1.0f);
}
__device__ __forceinline__ float b2f(unsigned short u) {
  return __uint_as_float((unsigned int)u << 16);
}
__device__ __forceinline__ unsigned short f2b(float f) {
  unsigned int u = __float_as_uint(f);
  u += 0x7FFFu + ((u >> 16) & 1u);   // round-to-nearest-even
  return (unsigned short)(u >> 16);
}

// C[m][n] = sum_k A[arow(m)][k] * W[n][k] + bias1[n] (+bias2[n]); optional tanh.
// A: fp32 or bf16 (ushort). C: fp32 or bf16. W/bias: fp32.
template<int K, int SWAP, int TANH, typename AT, typename CT>
__global__ __launch_bounds__(256) void gemm_k(const AT* __restrict__ A,
    const float* __restrict__ W, const float* __restrict__ bias1,
    const float* __restrict__ bias2, CT* __restrict__ C, int N) {
  __shared__ float As[32 * 68];
  __shared__ float Ws[128 * 68];
  const int tid = threadIdx.x;
  const int m0 = blockIdx.x * 32;
  const int n0 = blockIdx.y * 128;
  const int c0 = tid & 31;
  const int i0 = (tid >> 5) << 2;
  float acc[4][4] = {};
  for (int kc = 0; kc < K; kc += 64) {
    if constexpr (sizeof(AT) == 4) {
      int idx = tid;
#pragma unroll
      for (int q = 0; q < 2; ++q) {
        int row = idx >> 4, kq = idx & 15;
        int m = m0 + row;
        int ar = SWAP ? ((m & 255) * Tt + (m >> 8)) : m;  // x is [B][T][...]
        const float4 v = *reinterpret_cast<const float4*>(
            reinterpret_cast<const float*>(A) + (size_t)ar * K + kc + kq * 4);
        *reinterpret_cast<float4*>(&As[row * 68 + kq * 4]) = v;
        idx += 256;
      }
    } else {
      const int row = tid >> 3, g8 = (tid & 7) * 8;
      const unsigned short* src =
          reinterpret_cast<const unsigned short*>(A) + (size_t)(m0 + row) * K + kc + g8;
      const uint4 v = *reinterpret_cast<const uint4*>(src);
      float f[8];
      f[0] = b2f((unsigned short)(v.x & 0xFFFF)); f[1] = b2f((unsigned short)(v.x >> 16));
      f[2] = b2f((unsigned short)(v.y & 0xFFFF)); f[3] = b2f((unsigned short)(v.y >> 16));
      f[4] = b2f((unsigned short)(v.z & 0xFFFF)); f[5] = b2f((unsigned short)(v.z >> 16));
      f[6] = b2f((unsigned short)(v.w & 0xFFFF)); f[7] = b2f((unsigned short)(v.w >> 16));
      *reinterpret_cast<float4*>(&As[row * 68 + g8]) = make_float4(f[0], f[1], f[2], f[3]);
      *reinterpret_cast<float4*>(&As[row * 68 + g8 + 4]) = make_float4(f[4], f[5], f[6], f[7]);
    }
    {
      int idx = tid;
#pragma unroll
      for (int q = 0; q < 8; ++q) {
        int row = idx >> 4, kq = idx & 15;
        const float4 v = *reinterpret_cast<const float4*>(W + (size_t)(n0 + row) * K + kc + kq * 4);
        *reinterpret_cast<float4*>(&Ws[row * 68 + kq * 4]) = v;
        idx += 256;
      }
    }
    __syncthreads();
#pragma unroll
    for (int k4 = 0; k4 < 16; ++k4) {
      float4 a4[4], w4[4];
#pragma unroll
      for (int i = 0; i < 4; ++i)
        a4[i] = *reinterpret_cast<const float4*>(&As[(i0 + i) * 68 + k4 * 4]);
#pragma unroll
      for (int j = 0; j < 4; ++j)
        w4[j] = *reinterpret_cast<const float4*>(&Ws[(c0 + 32 * j) * 68 + k4 * 4]);
#pragma unroll
      for (int i = 0; i < 4; ++i)
#pragma unroll
        for (int j = 0; j < 4; ++j) {
          acc[i][j] += a4[i].x * w4[j].x;
          acc[i][j] += a4[i].y * w4[j].y;
          acc[i][j] += a4[i].z * w4[j].z;
          acc[i][j] += a4[i].w * w4[j].w;
        }
    }
    __syncthreads();
  }
#pragma unroll
  for (int j = 0; j < 4; ++j) {
    const int col = n0 + c0 + 32 * j;
    float bbv = bias1 ? bias1[col] : 0.0f;
    if (bias2) bbv += bias2[col];
#pragma unroll
    for (int i = 0; i < 4; ++i) {
      float v = acc[i][j] + bbv;
      if (TANH) v = tanhfast(v);
      const size_t oidx = (size_t)(m0 + i0 + i) * N + col;
      if constexpr (sizeof(CT) == 2) C[oidx] = f2b(v); else C[oidx] = v;
    }
  }
}

// MFMA bidirectional chunked LSTM.
// 256 blocks (dir = bid>>7, batch pair b0 = (bid&127)*2), 4 waves of 64.
// Wave w owns gate cols {gt*128 + w*32 .. +32} for gt=i,f,g,o; W_hh B-frags
// in VGPRs (bf16). h in LDS, A-frag-major [k-chunk][row][8], double-buffered,
// rows 2..15 zero-padded. Elementwise on lanes 0-15 (C-frag rows 0,1).
__global__ __launch_bounds__(256, 1) void lstm_k(const unsigned short* __restrict__ P,
    const float* __restrict__ Whh, const float* __restrict__ wtime,
    unsigned short* __restrict__ Y) {
  const int tid = threadIdx.x;
  const int lane = tid & 63;
  const int w = tid >> 6;
  const int u = lane & 15;
  const int q = lane >> 4;
  const int dir = blockIdx.x >> 7;
  const int b0 = (blockIdx.x & 127) * 2;

  __shared__ unsigned short hbuf[2][2048];   // [buf][kchunk16][row16][8]
  __shared__ unsigned int pgbuf[2][2][256];  // [buf][row][u32 of 2 bf16]
  __shared__ unsigned short histb[2048];     // [step&7][row2][col128]
  __shared__ float wts[32];

  // B fragments: bfrag[gt][t2][ks], lane: col = gt*128+w*32+t2*16+u, k = ks*32+q*8+j
  short8v bfrag[4][2][4];
#pragma unroll
  for (int gt = 0; gt < 4; ++gt)
#pragma unroll
    for (int t2 = 0; t2 < 2; ++t2) {
      const int col = gt * 128 + w * 32 + t2 * 16 + u;
#pragma unroll
      for (int ks = 0; ks < 4; ++ks) {
        const int k0 = ks * 32 + q * 8;
        const float4 w0 = *reinterpret_cast<const float4*>(Whh + (size_t)col * 128 + k0);
        const float4 w1 = *reinterpret_cast<const float4*>(Whh + (size_t)col * 128 + k0 + 4);
        short8v f;
        f[0] = (short)f2b(w0.x); f[1] = (short)f2b(w0.y);
        f[2] = (short)f2b(w0.z); f[3] = (short)f2b(w0.w);
        f[4] = (short)f2b(w1.x); f[5] = (short)f2b(w1.y);
        f[6] = (short)f2b(w1.z); f[7] = (short)f2b(w1.w);
        bfrag[gt][t2][ks] = f;
      }
    }

  for (int i = tid; i < 2048; i += 256) { hbuf[0][i] = 0; hbuf[1][i] = 0; }
  if (tid < 32) wts[tid] = wtime[tid];
  const unsigned int* P32 = reinterpret_cast<const unsigned int*>(P);
  {
    const int trow0 = dir ? (Tt - 1) : 0;
    pgbuf[0][0][tid] = P32[((size_t)trow0 * Bb + b0) * 256 + tid];
    pgbuf[0][1][tid] = P32[((size_t)trow0 * Bb + b0 + 1) * 256 + tid];
  }
  float c_st[2][2] = {}, ha[2][2] = {}, ca[2][2] = {};
  int cur = 0;
  __syncthreads();

  for (int s = 0; s < Tt; ++s) {
    if ((s & 7) == 0 && s) {  // flush 8 buffered output steps, coalesced
      const int rs = tid >> 4, inner = tid & 15;
      const int k = rs >> 1, r = rs & 1;
      const uint4 v = *reinterpret_cast<const uint4*>(&histb[(k * 2 + r) * 128 + inner * 8]);
      *reinterpret_cast<uint4*>(&Y[((size_t)(s - 8 + k) * Bb + b0 + r) * Dp + dir * Hh + inner * 8]) = v;
      __syncthreads();  // protect hist slot s&7==0 from this step's overwrite
    }
    // prefetch next step's pre-gates (coalesced, all threads)
    unsigned int np0 = 0, np1 = 0;
    if (s < Tt - 1) {
      const int trn = dir ? (Tt - 2 - s) : (s + 1);
      np0 = P32[((size_t)trn * Bb + b0) * 256 + tid];
      np1 = P32[((size_t)trn * Bb + b0 + 1) * 256 + tid];
    }
    // A fragments from h
    short8v afrag[4];
#pragma unroll
    for (int ks = 0; ks < 4; ++ks)
      afrag[ks] = *reinterpret_cast<const short8v*>(&hbuf[cur][(ks * 4 + q) * 128 + u * 8]);
    // gates = h @ Whh^T
    f32x4 gacc[4][2];
#pragma unroll
    for (int gt = 0; gt < 4; ++gt)
#pragma unroll
      for (int t2 = 0; t2 < 2; ++t2) {
        f32x4 acc = {0.f, 0.f, 0.f, 0.f};
#pragma unroll
        for (int ks = 0; ks < 4; ++ks)
          acc = __builtin_amdgcn_mfma_f32_16x16x32_bf16(afrag[ks], bfrag[gt][t2][ks], acc, 0, 0, 0);
        gacc[gt][t2] = acc;
      }
    // elementwise on C-frag rows 0,1 (lanes 0-15, regs 0,1)
    if (lane < 16) {
      const float wt = wts[s & 31];
      const bool ce = (s & 31) == 31;
#pragma unroll
      for (int t2 = 0; t2 < 2; ++t2) {
        const int colh = w * 32 + t2 * 16 + u;
#pragma unroll
        for (int r = 0; r < 2; ++r) {
          float g4[4];
#pragma unroll
          for (int gt = 0; gt < 4; ++gt) {
            const int c512 = gt * 128 + colh;
            const unsigned int pw = pgbuf[cur][r][c512 >> 1];
            const unsigned short pb = (c512 & 1) ? (unsigned short)(pw >> 16)
                                                 : (unsigned short)(pw & 0xFFFF);
            g4[gt] = gacc[gt][t2][r] + b2f(pb);
          }
          float cs = sigf(g4[1]) * c_st[t2][r] + sigf(g4[0]) * tanhfast(g4[2]);
          float hn = sigf(g4[3]) * tanhfast(cs);
          ha[t2][r] += wt * hn;
          ca[t2][r] += wt * cs;
          if (ce) { hn = ha[t2][r]; cs = ca[t2][r]; ha[t2][r] = 0.f; ca[t2][r] = 0.f; }
          c_st[t2][r] = cs;
          const unsigned short hb = f2b(hn);
          hbuf[cur ^ 1][(colh >> 3) * 128 + r * 8 + (colh & 7)] = hb;
          histb[((s & 7) * 2 + r) * 128 + colh] = hb;
        }
      }
    }
    if (s < Tt - 1) {
      pgbuf[cur ^ 1][0][tid] = np0;
      pgbuf[cur ^ 1][1][tid] = np1;
    }
    __syncthreads();
    cur ^= 1;
  }
  {  // final flush (steps 504..511)
    const int rs = tid >> 4, inner = tid & 15;
    const int k = rs >> 1, r = rs & 1;
    const uint4 v = *reinterpret_cast<const uint4*>(&histb[(k * 2 + r) * 128 + inner * 8]);
    *reinterpret_cast<uint4*>(&Y[((size_t)(Tt - 8 + k) * Bb + b0 + r) * Dp + dir * Hh + inner * 8]) = v;
  }
}

// pot[m][r] = tmp[m][:] . W_a2[r][:]   (tmp fp32)
__global__ __launch_bounds__(256) void pot_k(const float* __restrict__ tmp,
    const float* __restrict__ Wa2, float* __restrict__ pot) {
  const int tid = threadIdx.x;
  const int row = blockIdx.x * 32 + (tid >> 3);
  const int r = tid & 7;
  __shared__ float w2[8 * 129];
  for (int i = tid; i < 1024; i += 256) w2[(i >> 7) * 129 + (i & 127)] = Wa2[i];
  __syncthreads();
  float acc = 0.f;
  const float* tr = tmp + (size_t)row * 128;
#pragma unroll
  for (int k4 = 0; k4 < 32; ++k4) {
    const float4 tv = *reinterpret_cast<const float4*>(tr + k4 * 4);
    acc += tv.x * w2[r * 129 + k4 * 4 + 0];
    acc += tv.y * w2[r * 129 + k4 * 4 + 1];
    acc += tv.z * w2[r * 129 + k4 * 4 + 2];
    acc += tv.w * w2[r * 129 + k4 * 4 + 3];
  }
  pot[(size_t)row * 8 + r] = acc;
}

// masked softmax over t for one (b,r); writes Wt[b][r][t]
__global__ __launch_bounds__(256) void softmax_k(const float* __restrict__ pot,
    const int* __restrict__ length, float* __restrict__ Wt) {
  const int b = blockIdx.x >> 3, r = blockIdx.x & 7;
  const int tid = threadIdx.x;
  const int len = length[b];
  __shared__ float rbuf[4];
  const int t1 = tid, t2 = tid + 256;
  const float x1 = (t1 < len) ? pot[((size_t)t1 * Bb + b) * 8 + r] : -INFINITY;
  const float x2 = (t2 < len) ? pot[((size_t)t2 * Bb + b) * 8 + r] : -INFINITY;
  float m = fmaxf(x1, x2);
#pragma unroll
  for (int off = 32; off >= 1; off >>= 1) m = fmaxf(m, __shfl_xor(m, off));
  if ((tid & 63) == 0) rbuf[tid >> 6] = m;
  __syncthreads();
  m = fmaxf(fmaxf(rbuf[0], rbuf[1]), fmaxf(rbuf[2], rbuf[3]));
  const float e1 = (t1 < len) ? __expf(x1 - m) : 0.f;
  const float e2 = (t2 < len) ? __expf(x2 - m) : 0.f;
  float ssum = e1 + e2;
#pragma unroll
  for (int off = 32; off >= 1; off >>= 1) ssum += __shfl_xor(ssum, off);
  __syncthreads();
  if ((tid & 63) == 0) rbuf[tid >> 6] = ssum;
  __syncthreads();
  ssum = rbuf[0] + rbuf[1] + rbuf[2] + rbuf[3];
  const float inv = 1.0f / ssum;
  float* wrow = Wt + ((size_t)b * 8 + r) * Tt;
  wrow[t1] = e1 * inv;
  wrow[t2] = e2 * inv;
}

// Per-b: pooled = sum_t w[r][t]*Y[t][b][:], logits, log_softmax, gram penalty.
__global__ __launch_bounds__(256) void pool_k(const unsigned short* __restrict__ Y,
    const float* __restrict__ Wt, const float* __restrict__ Wout,
    const float* __restrict__ bout, float* __restrict__ outF,
    float* __restrict__ penpart) {
  const int b = blockIdx.x;
  const int tid = threadIdx.x;
  __shared__ float ws[8 * 513];
  __shared__ float pooled[2048];
  __shared__ float red[256];
  __shared__ float lg[8];
  for (int i = tid; i < 4096; i += 256) ws[(i >> 9) * 513 + (i & 511)] = Wt[(size_t)b * 4096 + i];
  __syncthreads();
  float acc[8] = {};
  for (int t = 0; t < Tt; ++t) {
    const float y = b2f(Y[((size_t)t * Bb + b) * Dp + tid]);
#pragma unroll
    for (int r = 0; r < 8; ++r) acc[r] += ws[r * 513 + t] * y;
  }
#pragma unroll
  for (int r = 0; r < 8; ++r) pooled[r * 256 + tid] = acc[r];
  __syncthreads();
  for (int o = 0; o < 7; ++o) {
    float p = 0.f;
    for (int j = tid; j < 2048; j += 256) p += pooled[j] * Wout[(size_t)o * 2048 + j];
    red[tid] = p;
    __syncthreads();
    for (int st = 128; st >= 1; st >>= 1) {
      if (tid < st) red[tid] += red[tid + st];
      __syncthreads();
    }
    if (tid == 0) lg[o] = red[0] + bout[o];
    __syncthreads();
  }
  if (tid == 0) {
    float mx = lg[0];
    for (int o = 1; o < 7; ++o) mx = fmaxf(mx, lg[o]);
    float ssum = 0.f;
    for (int o = 0; o < 7; ++o) ssum += __expf(lg[o] - mx);
    const float lse = mx + __logf(ssum);
    for (int o = 0; o < 7; ++o) outF[b * 7 + o] = lg[o] - lse;
  }
  for (int i = tid; i < 4096; i += 256) {
    const int rr = i >> 9, t = i & 511;
    ws[rr * 513 + t] = sqrtf(ws[rr * 513 + t]);
  }
  __syncthreads();
  float pp = 0.f;
  if (tid < 64) {
    const int rr = tid >> 3, ssi = tid & 7;
    float g = 0.f;
    for (int t = 0; t < Tt; ++t) g += ws[rr * 513 + t] * ws[ssi * 513 + t];
    const float d = g - 1.0f;
    pp = d * d;
  }
  red[tid] = pp;
  __syncthreads();
  for (int st = 128; st >= 1; st >>= 1) {
    if (tid < st) red[tid] += red[tid + st];
    __syncthreads();
  }
  if (tid == 0) penpart[b] = red[0];
}

__global__ __launch_bounds__(256) void penred_k(const float* __restrict__ penpart,
                                                float* __restrict__ outp) {
  const int tid = threadIdx.x;
  __shared__ float red[256];
  red[tid] = penpart[tid];
  __syncthreads();
  for (int st = 128; st >= 1; st >>= 1) {
    if (tid < st) red[tid] += red[tid + st];
    __syncthreads();
  }
  if (tid == 0) outp[0] = red[0];
}

} // namespace

extern "C" void kernel_launch(void* const* d_in, const int* in_sizes, int n_in,
                              void* d_out, int out_size, void* d_ws, size_t ws_size,
                              hipStream_t stream) {
  (void)in_sizes; (void)n_in; (void)out_size;
  const float* x     = (const float*)d_in[0];
  const float* W_in  = (const float*)d_in[1];
  const float* b_in  = (const float*)d_in[2];
  const float* W_ih  = (const float*)d_in[3];
  const float* b_ih  = (const float*)d_in[4];
  const float* W_hh  = (const float*)d_in[5];
  const float* b_hh  = (const float*)d_in[6];
  const float* wtime = (const float*)d_in[7];
  const float* W_a1  = (const float*)d_in[8];
  const float* b_a1  = (const float*)d_in[9];
  const float* W_a2  = (const float*)d_in[10];
  const float* W_out = (const float*)d_in[11];
  const float* b_out = (const float*)d_in[12];
  const int*   length= (const int*)d_in[13];
  float* outF = (float*)d_out;

  typedef unsigned short bf16;
  char* ws = (char*)d_ws;
  size_t off = 0;
  auto alloc = [&](size_t bytes) {
    void* p = ws + off; off += (bytes + 255) & ~(size_t)255; return p;
  };
  bf16*  act  = (bf16*)alloc((size_t)M * 256 * 2);   // activations [T*B][256], bf16
  bf16*  Pg   = (bf16*)alloc((size_t)M * 512 * 2);   // pre-gates  [T*B][512], bf16
  float* pot  = (float*)alloc((size_t)M * 8 * 4);
  float* Wt   = (float*)alloc((size_t)Bb * 8 * Tt * 4);
  float* penp = (float*)alloc(Bb * 4);
  float* tmpA = (float*)Pg;  // attention tanh activations [M][128] fp32, aliases dead Pg

  if (ws_size < off) return;  // workspace too small: clean absmax-fail, not a crash

  const dim3 blk(256);
  // input layer: rows (t,b) <- x[b][t][:]
  gemm_k<128, 1, 0, float, bf16><<<dim3(M / 32, 2), blk, 0, stream>>>(x, W_in, b_in, nullptr, act, 256);
  // layer 0
  gemm_k<256, 0, 0, bf16, bf16><<<dim3(M / 32, 4), blk, 0, stream>>>(act, W_ih, b_ih, b_hh, Pg, 512);
  lstm_k<<<dim3(256), blk, 0, stream>>>(Pg, W_hh, wtime, act);
  // layer 1 (shared weights)
  gemm_k<256, 0, 0, bf16, bf16><<<dim3(M / 32, 4), blk, 0, stream>>>(act, W_ih, b_ih, b_hh, Pg, 512);
  lstm_k<<<dim3(256), blk, 0, stream>>>(Pg, W_hh, wtime, act);
  // attention
  gemm_k<256, 0, 1, bf16, float><<<dim3(M / 32, 1), blk, 0, stream>>>(act, W_a1, b_a1, nullptr, tmpA, 128);
  pot_k<<<dim3(M / 32), blk, 0, stream>>>(tmpA, W_a2, pot);
  softmax_k<<<dim3(Bb * 8), blk, 0, stream>>>(pot, length, Wt);
  pool_k<<<dim3(Bb), blk, 0, stream>>>(act, Wt, W_out, b_out, outF, penp);
  penred_k<<<dim3(1), blk, 0, stream>>>(penp, outF + Bb * 7);
}

// Round 4
// 1828.135 us; speedup vs baseline: 1.9099x; 1.7245x over previous
//
#include <hip/hip_runtime.h>
#include <math.h>

namespace {

constexpr int Bb = 256, Tt = 512, Dp = 256, Hh = 128, G = 512;
constexpr int M = Tt * Bb; // 131072 rows (t-major: row = t*B + b)

typedef __attribute__((ext_vector_type(8))) short short8v;
typedef __attribute__((ext_vector_type(4))) float f32x4;

__device__ __forceinline__ float sigf(float x) { return 1.0f / (1.0f + __expf(-x)); }
__device__ __forceinline__ float tanhfast(float x) {
  x = fminf(15.0f, fmaxf(-15.0f, x));
  float e = __expf(2.0f * x);
  return (e - 1.0f) / (e + 1.0f);
}
__device__ __forceinline__ float b2f(unsigned short u) {
  return __uint_as_float((unsigned int)u << 16);
}
__device__ __forceinline__ unsigned short f2b(float f) {
  unsigned int u = __float_as_uint(f);
  u += 0x7FFFu + ((u >> 16) & 1u);   // round-to-nearest-even
  return (unsigned short)(u >> 16);
}
__device__ __forceinline__ unsigned int pack2(float a, float b) {
  return (unsigned int)f2b(a) | ((unsigned int)f2b(b) << 16);
}

// MFMA GEMM: C[m][n] = sum_k A[arow(m)][k]*W[n][k] + bias1[n] (+bias2[n]); opt tanh.
// 128x128 tile, 4 waves (64x64 quadrant each), BK=64 double-buffered LDS.
// LDS layout fragment-major: [kc][frag16][lane][8] -> lane-linear b128 reads.
// A: bf16 or fp32(+SWAP for x[B][T][.]); W fp32 -> bf16 at stage time.
template<int K, int SWAP, int TANH, typename AT, typename CT>
__global__ __launch_bounds__(256) void mgemm_k(const AT* __restrict__ A,
    const float* __restrict__ W, const float* __restrict__ bias1,
    const float* __restrict__ bias2, CT* __restrict__ C, int N) {
  constexpr int NK = K / 64;
  __shared__ unsigned short aLds[2][8192];  // [buf][(kc*8+mf)*64+lane][8]
  __shared__ unsigned short wLds[2][8192];
  const int tid = threadIdx.x;
  const int lane = tid & 63;
  const int wave = tid >> 6;
  const int wm = wave >> 1, wn = wave & 1;
  const int m0 = blockIdx.y * 128, n0 = blockIdx.x * 128;

  const int srow = tid >> 1;   // 0..127: A-tile row / W-tile col
  const int skc = tid & 1;     // k-half of the 64-wide K step
  int am;
  if constexpr (SWAP) { const int m = m0 + srow; am = (m & 255) * Tt + (m >> 8); }
  else am = m0 + srow;

  uint4 ra[4];          // staged A (bf16 path)
  float4 raf[4][2];     // staged A (fp32 path)
  float4 rw[4][2];      // staged W (fp32)

  auto loadA = [&](int kb) {
    const int kbase = kb * 64 + skc * 32;
    if constexpr (sizeof(AT) == 2) {
      const unsigned short* src = reinterpret_cast<const unsigned short*>(A) + (size_t)am * K + kbase;
#pragma unroll
      for (int q = 0; q < 4; ++q) ra[q] = *reinterpret_cast<const uint4*>(src + q * 8);
    } else {
      const float* src = reinterpret_cast<const float*>(A) + (size_t)am * K + kbase;
#pragma unroll
      for (int q = 0; q < 4; ++q) {
        raf[q][0] = *reinterpret_cast<const float4*>(src + q * 8);
        raf[q][1] = *reinterpret_cast<const float4*>(src + q * 8 + 4);
      }
    }
  };
  auto loadW = [&](int kb) {
    const int kbase = kb * 64 + skc * 32;
    const float* src = W + (size_t)(n0 + srow) * K + kbase;
#pragma unroll
    for (int q = 0; q < 4; ++q) {
      rw[q][0] = *reinterpret_cast<const float4*>(src + q * 8);
      rw[q][1] = *reinterpret_cast<const float4*>(src + q * 8 + 4);
    }
  };
  auto writeS = [&](int buf) {
    const int base = (skc * 8 + (srow >> 4)) * 64 + (srow & 15);  // + q*16
#pragma unroll
    for (int q = 0; q < 4; ++q) {
      const int slot = base + q * 16;
      if constexpr (sizeof(AT) == 2) {
        *reinterpret_cast<uint4*>(&aLds[buf][slot * 8]) = ra[q];
      } else {
        uint4 p;
        p.x = pack2(raf[q][0].x, raf[q][0].y); p.y = pack2(raf[q][0].z, raf[q][0].w);
        p.z = pack2(raf[q][1].x, raf[q][1].y); p.w = pack2(raf[q][1].z, raf[q][1].w);
        *reinterpret_cast<uint4*>(&aLds[buf][slot * 8]) = p;
      }
      uint4 pw;
      pw.x = pack2(rw[q][0].x, rw[q][0].y); pw.y = pack2(rw[q][0].z, rw[q][0].w);
      pw.z = pack2(rw[q][1].x, rw[q][1].y); pw.w = pack2(rw[q][1].z, rw[q][1].w);
      *reinterpret_cast<uint4*>(&wLds[buf][slot * 8]) = pw;
    }
  };

  f32x4 acc[4][4] = {};
  int cur = 0;
  loadA(0); loadW(0); writeS(0);
  __syncthreads();
  for (int kb = 0; kb < NK; ++kb) {
    const bool more = (kb + 1 < NK);
    if (more) { loadA(kb + 1); loadW(kb + 1); }  // prefetch into regs
#pragma unroll
    for (int kc = 0; kc < 2; ++kc) {
      short8v af[4], bfr[4];
#pragma unroll
      for (int i = 0; i < 4; ++i)
        af[i] = *reinterpret_cast<const short8v*>(
            &aLds[cur][((kc * 8 + wm * 4 + i) * 64 + lane) * 8]);
#pragma unroll
      for (int j = 0; j < 4; ++j)
        bfr[j] = *reinterpret_cast<const short8v*>(
            &wLds[cur][((kc * 8 + wn * 4 + j) * 64 + lane) * 8]);
#pragma unroll
      for (int i = 0; i < 4; ++i)
#pragma unroll
        for (int j = 0; j < 4; ++j)
          acc[i][j] = __builtin_amdgcn_mfma_f32_16x16x32_bf16(af[i], bfr[j], acc[i][j], 0, 0, 0);
    }
    if (more) writeS(cur ^ 1);
    __syncthreads();
    cur ^= 1;
  }
  // epilogue: C/D frag mapping col=lane&15, row=(lane>>4)*4+reg
#pragma unroll
  for (int j = 0; j < 4; ++j) {
    const int gn = n0 + wn * 64 + j * 16 + (lane & 15);
    float bv = bias1[gn];
    if (bias2) bv += bias2[gn];
#pragma unroll
    for (int i = 0; i < 4; ++i) {
      const int gmb = m0 + wm * 64 + i * 16 + ((lane >> 4) << 2);
#pragma unroll
      for (int r = 0; r < 4; ++r) {
        float v = acc[i][j][r] + bv;
        if (TANH) v = tanhfast(v);
        const size_t oidx = (size_t)(gmb + r) * N + gn;
        if constexpr (sizeof(CT) == 2) C[oidx] = f2b(v); else C[oidx] = v;
      }
    }
  }
}

// MFMA bidirectional chunked LSTM (unchanged from round 3).
__global__ __launch_bounds__(256, 1) void lstm_k(const unsigned short* __restrict__ P,
    const float* __restrict__ Whh, const float* __restrict__ wtime,
    unsigned short* __restrict__ Y) {
  const int tid = threadIdx.x;
  const int lane = tid & 63;
  const int w = tid >> 6;
  const int u = lane & 15;
  const int q = lane >> 4;
  const int dir = blockIdx.x >> 7;
  const int b0 = (blockIdx.x & 127) * 2;

  __shared__ unsigned short hbuf[2][2048];
  __shared__ unsigned int pgbuf[2][2][256];
  __shared__ unsigned short histb[2048];
  __shared__ float wts[32];

  short8v bfrag[4][2][4];
#pragma unroll
  for (int gt = 0; gt < 4; ++gt)
#pragma unroll
    for (int t2 = 0; t2 < 2; ++t2) {
      const int col = gt * 128 + w * 32 + t2 * 16 + u;
#pragma unroll
      for (int ks = 0; ks < 4; ++ks) {
        const int k0 = ks * 32 + q * 8;
        const float4 w0 = *reinterpret_cast<const float4*>(Whh + (size_t)col * 128 + k0);
        const float4 w1 = *reinterpret_cast<const float4*>(Whh + (size_t)col * 128 + k0 + 4);
        short8v f;
        f[0] = (short)f2b(w0.x); f[1] = (short)f2b(w0.y);
        f[2] = (short)f2b(w0.z); f[3] = (short)f2b(w0.w);
        f[4] = (short)f2b(w1.x); f[5] = (short)f2b(w1.y);
        f[6] = (short)f2b(w1.z); f[7] = (short)f2b(w1.w);
        bfrag[gt][t2][ks] = f;
      }
    }

  for (int i = tid; i < 2048; i += 256) { hbuf[0][i] = 0; hbuf[1][i] = 0; }
  if (tid < 32) wts[tid] = wtime[tid];
  const unsigned int* P32 = reinterpret_cast<const unsigned int*>(P);
  {
    const int trow0 = dir ? (Tt - 1) : 0;
    pgbuf[0][0][tid] = P32[((size_t)trow0 * Bb + b0) * 256 + tid];
    pgbuf[0][1][tid] = P32[((size_t)trow0 * Bb + b0 + 1) * 256 + tid];
  }
  float c_st[2][2] = {}, ha[2][2] = {}, ca[2][2] = {};
  int cur = 0;
  __syncthreads();

  for (int s = 0; s < Tt; ++s) {
    if ((s & 7) == 0 && s) {
      const int rs = tid >> 4, inner = tid & 15;
      const int k = rs >> 1, r = rs & 1;
      const uint4 v = *reinterpret_cast<const uint4*>(&histb[(k * 2 + r) * 128 + inner * 8]);
      *reinterpret_cast<uint4*>(&Y[((size_t)(s - 8 + k) * Bb + b0 + r) * Dp + dir * Hh + inner * 8]) = v;
      __syncthreads();
    }
    unsigned int np0 = 0, np1 = 0;
    if (s < Tt - 1) {
      const int trn = dir ? (Tt - 2 - s) : (s + 1);
      np0 = P32[((size_t)trn * Bb + b0) * 256 + tid];
      np1 = P32[((size_t)trn * Bb + b0 + 1) * 256 + tid];
    }
    short8v afrag[4];
#pragma unroll
    for (int ks = 0; ks < 4; ++ks)
      afrag[ks] = *reinterpret_cast<const short8v*>(&hbuf[cur][(ks * 4 + q) * 128 + u * 8]);
    f32x4 gacc[4][2];
#pragma unroll
    for (int gt = 0; gt < 4; ++gt)
#pragma unroll
      for (int t2 = 0; t2 < 2; ++t2) {
        f32x4 acc = {0.f, 0.f, 0.f, 0.f};
#pragma unroll
        for (int ks = 0; ks < 4; ++ks)
          acc = __builtin_amdgcn_mfma_f32_16x16x32_bf16(afrag[ks], bfrag[gt][t2][ks], acc, 0, 0, 0);
        gacc[gt][t2] = acc;
      }
    if (lane < 16) {
      const float wt = wts[s & 31];
      const bool ce = (s & 31) == 31;
#pragma unroll
      for (int t2 = 0; t2 < 2; ++t2) {
        const int colh = w * 32 + t2 * 16 + u;
#pragma unroll
        for (int r = 0; r < 2; ++r) {
          float g4[4];
#pragma unroll
          for (int gt = 0; gt < 4; ++gt) {
            const int c512 = gt * 128 + colh;
            const unsigned int pw = pgbuf[cur][r][c512 >> 1];
            const unsigned short pb = (c512 & 1) ? (unsigned short)(pw >> 16)
                                                 : (unsigned short)(pw & 0xFFFF);
            g4[gt] = gacc[gt][t2][r] + b2f(pb);
          }
          float cs = sigf(g4[1]) * c_st[t2][r] + sigf(g4[0]) * tanhfast(g4[2]);
          float hn = sigf(g4[3]) * tanhfast(cs);
          ha[t2][r] += wt * hn;
          ca[t2][r] += wt * cs;
          if (ce) { hn = ha[t2][r]; cs = ca[t2][r]; ha[t2][r] = 0.f; ca[t2][r] = 0.f; }
          c_st[t2][r] = cs;
          const unsigned short hb = f2b(hn);
          hbuf[cur ^ 1][(colh >> 3) * 128 + r * 8 + (colh & 7)] = hb;
          histb[((s & 7) * 2 + r) * 128 + colh] = hb;
        }
      }
    }
    if (s < Tt - 1) {
      pgbuf[cur ^ 1][0][tid] = np0;
      pgbuf[cur ^ 1][1][tid] = np1;
    }
    __syncthreads();
    cur ^= 1;
  }
  {
    const int rs = tid >> 4, inner = tid & 15;
    const int k = rs >> 1, r = rs & 1;
    const uint4 v = *reinterpret_cast<const uint4*>(&histb[(k * 2 + r) * 128 + inner * 8]);
    *reinterpret_cast<uint4*>(&Y[((size_t)(Tt - 8 + k) * Bb + b0 + r) * Dp + dir * Hh + inner * 8]) = v;
  }
}

// pot[m][r] = tmp[m][:] . W_a2[r][:]   (tmp fp32)
__global__ __launch_bounds__(256) void pot_k(const float* __restrict__ tmp,
    const float* __restrict__ Wa2, float* __restrict__ pot) {
  const int tid = threadIdx.x;
  const int row = blockIdx.x * 32 + (tid >> 3);
  const int r = tid & 7;
  __shared__ float w2[8 * 129];
  for (int i = tid; i < 1024; i += 256) w2[(i >> 7) * 129 + (i & 127)] = Wa2[i];
  __syncthreads();
  float acc = 0.f;
  const float* tr = tmp + (size_t)row * 128;
#pragma unroll
  for (int k4 = 0; k4 < 32; ++k4) {
    const float4 tv = *reinterpret_cast<const float4*>(tr + k4 * 4);
    acc += tv.x * w2[r * 129 + k4 * 4 + 0];
    acc += tv.y * w2[r * 129 + k4 * 4 + 1];
    acc += tv.z * w2[r * 129 + k4 * 4 + 2];
    acc += tv.w * w2[r * 129 + k4 * 4 + 3];
  }
  pot[(size_t)row * 8 + r] = acc;
}

// masked softmax over t for one (b,r); writes Wt[b][r][t]
__global__ __launch_bounds__(256) void softmax_k(const float* __restrict__ pot,
    const int* __restrict__ length, float* __restrict__ Wt) {
  const int b = blockIdx.x >> 3, r = blockIdx.x & 7;
  const int tid = threadIdx.x;
  const int len = length[b];
  __shared__ float rbuf[4];
  const int t1 = tid, t2 = tid + 256;
  const float x1 = (t1 < len) ? pot[((size_t)t1 * Bb + b) * 8 + r] : -INFINITY;
  const float x2 = (t2 < len) ? pot[((size_t)t2 * Bb + b) * 8 + r] : -INFINITY;
  float m = fmaxf(x1, x2);
#pragma unroll
  for (int off = 32; off >= 1; off >>= 1) m = fmaxf(m, __shfl_xor(m, off));
  if ((tid & 63) == 0) rbuf[tid >> 6] = m;
  __syncthreads();
  m = fmaxf(fmaxf(rbuf[0], rbuf[1]), fmaxf(rbuf[2], rbuf[3]));
  const float e1 = (t1 < len) ? __expf(x1 - m) : 0.f;
  const float e2 = (t2 < len) ? __expf(x2 - m) : 0.f;
  float ssum = e1 + e2;
#pragma unroll
  for (int off = 32; off >= 1; off >>= 1) ssum += __shfl_xor(ssum, off);
  __syncthreads();
  if ((tid & 63) == 0) rbuf[tid >> 6] = ssum;
  __syncthreads();
  ssum = rbuf[0] + rbuf[1] + rbuf[2] + rbuf[3];
  const float inv = 1.0f / ssum;
  float* wrow = Wt + ((size_t)b * 8 + r) * Tt;
  wrow[t1] = e1 * inv;
  wrow[t2] = e2 * inv;
}

// Per-b: pooled = sum_t w[r][t]*Y[t][b][:], logits, log_softmax, gram penalty.
__global__ __launch_bounds__(256) void pool_k(const unsigned short* __restrict__ Y,
    const float* __restrict__ Wt, const float* __restrict__ Wout,
    const float* __restrict__ bout, float* __restrict__ outF,
    float* __restrict__ penpart) {
  const int b = blockIdx.x;
  const int tid = threadIdx.x;
  __shared__ float ws[8 * 513];
  __shared__ float pooled[2048];
  __shared__ float red[256];
  __shared__ float lg[8];
  for (int i = tid; i < 4096; i += 256) ws[(i >> 9) * 513 + (i & 511)] = Wt[(size_t)b * 4096 + i];
  __syncthreads();
  float acc[8] = {};
  for (int t = 0; t < Tt; ++t) {
    const float y = b2f(Y[((size_t)t * Bb + b) * Dp + tid]);
#pragma unroll
    for (int r = 0; r < 8; ++r) acc[r] += ws[r * 513 + t] * y;
  }
#pragma unroll
  for (int r = 0; r < 8; ++r) pooled[r * 256 + tid] = acc[r];
  __syncthreads();
  for (int o = 0; o < 7; ++o) {
    float p = 0.f;
    for (int j = tid; j < 2048; j += 256) p += pooled[j] * Wout[(size_t)o * 2048 + j];
    red[tid] = p;
    __syncthreads();
    for (int st = 128; st >= 1; st >>= 1) {
      if (tid < st) red[tid] += red[tid + st];
      __syncthreads();
    }
    if (tid == 0) lg[o] = red[0] + bout[o];
    __syncthreads();
  }
  if (tid == 0) {
    float mx = lg[0];
    for (int o = 1; o < 7; ++o) mx = fmaxf(mx, lg[o]);
    float ssum = 0.f;
    for (int o = 0; o < 7; ++o) ssum += __expf(lg[o] - mx);
    const float lse = mx + __logf(ssum);
    for (int o = 0; o < 7; ++o) outF[b * 7 + o] = lg[o] - lse;
  }
  for (int i = tid; i < 4096; i += 256) {
    const int rr = i >> 9, t = i & 511;
    ws[rr * 513 + t] = sqrtf(ws[rr * 513 + t]);
  }
  __syncthreads();
  float pp = 0.f;
  if (tid < 64) {
    const int rr = tid >> 3, ssi = tid & 7;
    float g = 0.f;
    for (int t = 0; t < Tt; ++t) g += ws[rr * 513 + t] * ws[ssi * 513 + t];
    const float d = g - 1.0f;
    pp = d * d;
  }
  red[tid] = pp;
  __syncthreads();
  for (int st = 128; st >= 1; st >>= 1) {
    if (tid < st) red[tid] += red[tid + st];
    __syncthreads();
  }
  if (tid == 0) penpart[b] = red[0];
}

__global__ __launch_bounds__(256) void penred_k(const float* __restrict__ penpart,
                                                float* __restrict__ outp) {
  const int tid = threadIdx.x;
  __shared__ float red[256];
  red[tid] = penpart[tid];
  __syncthreads();
  for (int st = 128; st >= 1; st >>= 1) {
    if (tid < st) red[tid] += red[tid + st];
    __syncthreads();
  }
  if (tid == 0) outp[0] = red[0];
}

} // namespace

extern "C" void kernel_launch(void* const* d_in, const int* in_sizes, int n_in,
                              void* d_out, int out_size, void* d_ws, size_t ws_size,
                              hipStream_t stream) {
  (void)in_sizes; (void)n_in; (void)out_size;
  const float* x     = (const float*)d_in[0];
  const float* W_in  = (const float*)d_in[1];
  const float* b_in  = (const float*)d_in[2];
  const float* W_ih  = (const float*)d_in[3];
  const float* b_ih  = (const float*)d_in[4];
  const float* W_hh  = (const float*)d_in[5];
  const float* b_hh  = (const float*)d_in[6];
  const float* wtime = (const float*)d_in[7];
  const float* W_a1  = (const float*)d_in[8];
  const float* b_a1  = (const float*)d_in[9];
  const float* W_a2  = (const float*)d_in[10];
  const float* W_out = (const float*)d_in[11];
  const float* b_out = (const float*)d_in[12];
  const int*   length= (const int*)d_in[13];
  float* outF = (float*)d_out;

  typedef unsigned short bf16;
  char* ws = (char*)d_ws;
  size_t off = 0;
  auto alloc = [&](size_t bytes) {
    void* p = ws + off; off += (bytes + 255) & ~(size_t)255; return p;
  };
  bf16*  act  = (bf16*)alloc((size_t)M * 256 * 2);   // activations [T*B][256], bf16
  bf16*  Pg   = (bf16*)alloc((size_t)M * 512 * 2);   // pre-gates  [T*B][512], bf16
  float* pot  = (float*)alloc((size_t)M * 8 * 4);
  float* Wt   = (float*)alloc((size_t)Bb * 8 * Tt * 4);
  float* penp = (float*)alloc(Bb * 4);
  float* tmpA = (float*)Pg;  // attention tanh activations [M][128] fp32, aliases dead Pg

  if (ws_size < off) return;  // workspace too small: clean absmax-fail, not a crash

  const dim3 blk(256);
  // input layer: rows (t,b) <- x[b][t][:]
  mgemm_k<128, 1, 0, float, bf16><<<dim3(2, M / 128), blk, 0, stream>>>(x, W_in, b_in, nullptr, act, 256);
  // layer 0
  mgemm_k<256, 0, 0, bf16, bf16><<<dim3(4, M / 128), blk, 0, stream>>>(act, W_ih, b_ih, b_hh, Pg, 512);
  lstm_k<<<dim3(256), blk, 0, stream>>>(Pg, W_hh, wtime, act);
  // layer 1 (shared weights)
  mgemm_k<256, 0, 0, bf16, bf16><<<dim3(4, M / 128), blk, 0, stream>>>(act, W_ih, b_ih, b_hh, Pg, 512);
  lstm_k<<<dim3(256), blk, 0, stream>>>(Pg, W_hh, wtime, act);
  // attention
  mgemm_k<256, 0, 1, bf16, float><<<dim3(1, M / 128), blk, 0, stream>>>(act, W_a1, b_a1, nullptr, tmpA, 128);
  pot_k<<<dim3(M / 32), blk, 0, stream>>>(tmpA, W_a2, pot);
  softmax_k<<<dim3(Bb * 8), blk, 0, stream>>>(pot, length, Wt);
  pool_k<<<dim3(Bb), blk, 0, stream>>>(act, Wt, W_out, b_out, outF, penp);
  penred_k<<<dim3(1), blk, 0, stream>>>(penp, outF + Bb * 7);
}

// Round 5
// 1619.884 us; speedup vs baseline: 2.1554x; 1.1286x over previous
//
#include <hip/hip_runtime.h>
#include <math.h>

namespace {

constexpr int Bb = 256, Tt = 512, Dp = 256, Hh = 128, G = 512;
constexpr int M = Tt * Bb; // 131072 rows (t-major: row = t*B + b)

typedef __attribute__((ext_vector_type(8))) short short8v;
typedef __attribute__((ext_vector_type(4))) float f32x4;

__device__ __forceinline__ float sigf(float x) { return 1.0f / (1.0f + __expf(-x)); }
__device__ __forceinline__ float tanhfast(float x) {
  x = fminf(15.0f, fmaxf(-15.0f, x));
  float e = __expf(2.0f * x);
  return (e - 1.0f) / (e + 1.0f);
}
__device__ __forceinline__ float b2f(unsigned short u) {
  return __uint_as_float((unsigned int)u << 16);
}
__device__ __forceinline__ unsigned short f2b(float f) {
  unsigned int u = __float_as_uint(f);
  u += 0x7FFFu + ((u >> 16) & 1u);   // round-to-nearest-even
  return (unsigned short)(u >> 16);
}
__device__ __forceinline__ unsigned int pack2(float a, float b) {
  return (unsigned int)f2b(a) | ((unsigned int)f2b(b) << 16);
}

// MFMA GEMM: C[m][n] = sum_k A[arow(m)][k]*W[n][k] + bias1[n] (+bias2[n]); opt tanh.
// 128x128 tile, 4 waves (64x64 quadrant each), BK=64 double-buffered LDS.
template<int K, int SWAP, int TANH, typename AT, typename CT>
__global__ __launch_bounds__(256) void mgemm_k(const AT* __restrict__ A,
    const float* __restrict__ W, const float* __restrict__ bias1,
    const float* __restrict__ bias2, CT* __restrict__ C, int N) {
  constexpr int NK = K / 64;
  __shared__ unsigned short aLds[2][8192];  // [buf][(kc*8+mf)*64+lane][8]
  __shared__ unsigned short wLds[2][8192];
  const int tid = threadIdx.x;
  const int lane = tid & 63;
  const int wave = tid >> 6;
  const int wm = wave >> 1, wn = wave & 1;
  const int m0 = blockIdx.y * 128, n0 = blockIdx.x * 128;

  const int srow = tid >> 1;   // 0..127: A-tile row / W-tile col
  const int skc = tid & 1;     // k-half of the 64-wide K step
  int am;
  if constexpr (SWAP) { const int m = m0 + srow; am = (m & 255) * Tt + (m >> 8); }
  else am = m0 + srow;

  uint4 ra[4];
  float4 raf[4][2];
  float4 rw[4][2];

  auto loadA = [&](int kb) {
    const int kbase = kb * 64 + skc * 32;
    if constexpr (sizeof(AT) == 2) {
      const unsigned short* src = reinterpret_cast<const unsigned short*>(A) + (size_t)am * K + kbase;
#pragma unroll
      for (int q = 0; q < 4; ++q) ra[q] = *reinterpret_cast<const uint4*>(src + q * 8);
    } else {
      const float* src = reinterpret_cast<const float*>(A) + (size_t)am * K + kbase;
#pragma unroll
      for (int q = 0; q < 4; ++q) {
        raf[q][0] = *reinterpret_cast<const float4*>(src + q * 8);
        raf[q][1] = *reinterpret_cast<const float4*>(src + q * 8 + 4);
      }
    }
  };
  auto loadW = [&](int kb) {
    const int kbase = kb * 64 + skc * 32;
    const float* src = W + (size_t)(n0 + srow) * K + kbase;
#pragma unroll
    for (int q = 0; q < 4; ++q) {
      rw[q][0] = *reinterpret_cast<const float4*>(src + q * 8);
      rw[q][1] = *reinterpret_cast<const float4*>(src + q * 8 + 4);
    }
  };
  auto writeS = [&](int buf) {
    const int base = (skc * 8 + (srow >> 4)) * 64 + (srow & 15);
#pragma unroll
    for (int q = 0; q < 4; ++q) {
      const int slot = base + q * 16;
      if constexpr (sizeof(AT) == 2) {
        *reinterpret_cast<uint4*>(&aLds[buf][slot * 8]) = ra[q];
      } else {
        uint4 p;
        p.x = pack2(raf[q][0].x, raf[q][0].y); p.y = pack2(raf[q][0].z, raf[q][0].w);
        p.z = pack2(raf[q][1].x, raf[q][1].y); p.w = pack2(raf[q][1].z, raf[q][1].w);
        *reinterpret_cast<uint4*>(&aLds[buf][slot * 8]) = p;
      }
      uint4 pw;
      pw.x = pack2(rw[q][0].x, rw[q][0].y); pw.y = pack2(rw[q][0].z, rw[q][0].w);
      pw.z = pack2(rw[q][1].x, rw[q][1].y); pw.w = pack2(rw[q][1].z, rw[q][1].w);
      *reinterpret_cast<uint4*>(&wLds[buf][slot * 8]) = pw;
    }
  };

  f32x4 acc[4][4] = {};
  int cur = 0;
  loadA(0); loadW(0); writeS(0);
  __syncthreads();
  for (int kb = 0; kb < NK; ++kb) {
    const bool more = (kb + 1 < NK);
    if (more) { loadA(kb + 1); loadW(kb + 1); }
#pragma unroll
    for (int kc = 0; kc < 2; ++kc) {
      short8v af[4], bfr[4];
#pragma unroll
      for (int i = 0; i < 4; ++i)
        af[i] = *reinterpret_cast<const short8v*>(
            &aLds[cur][((kc * 8 + wm * 4 + i) * 64 + lane) * 8]);
#pragma unroll
      for (int j = 0; j < 4; ++j)
        bfr[j] = *reinterpret_cast<const short8v*>(
            &wLds[cur][((kc * 8 + wn * 4 + j) * 64 + lane) * 8]);
#pragma unroll
      for (int i = 0; i < 4; ++i)
#pragma unroll
        for (int j = 0; j < 4; ++j)
          acc[i][j] = __builtin_amdgcn_mfma_f32_16x16x32_bf16(af[i], bfr[j], acc[i][j], 0, 0, 0);
    }
    if (more) writeS(cur ^ 1);
    __syncthreads();
    cur ^= 1;
  }
#pragma unroll
  for (int j = 0; j < 4; ++j) {
    const int gn = n0 + wn * 64 + j * 16 + (lane & 15);
    float bv = bias1[gn];
    if (bias2) bv += bias2[gn];
#pragma unroll
    for (int i = 0; i < 4; ++i) {
      const int gmb = m0 + wm * 64 + i * 16 + ((lane >> 4) << 2);
#pragma unroll
      for (int r = 0; r < 4; ++r) {
        float v = acc[i][j][r] + bv;
        if (TANH) v = tanhfast(v);
        const size_t oidx = (size_t)(gmb + r) * N + gn;
        if constexpr (sizeof(CT) == 2) C[oidx] = f2b(v); else C[oidx] = v;
      }
    }
  }
}

// MFMA bidirectional chunked LSTM, 8 waves (2/SIMD for latency hiding).
// 256 blocks (dir = bid>>7, batch pair b0=(bid&127)*2), 512 threads.
// Wave w owns gate cols {gt*128 + w*16 + u}, gt=i,f,g,o; 16 MFMAs/step.
__global__ __launch_bounds__(512, 2) void lstm_k(const unsigned short* __restrict__ P,
    const float* __restrict__ Whh, const float* __restrict__ wtime,
    unsigned short* __restrict__ Y) {
  const int tid = threadIdx.x;
  const int lane = tid & 63;
  const int w = tid >> 6;        // wave 0..7
  const int u = lane & 15;
  const int q = lane >> 4;
  const int dir = blockIdx.x >> 7;
  const int b0 = (blockIdx.x & 127) * 2;

  __shared__ unsigned short hbuf[2][2048];   // [buf][koct16][row16][8]
  __shared__ unsigned int pgbuf[2][512];     // [buf][row*256 + word]
  __shared__ unsigned short histb[2048];     // [step&7][row2][col128]
  __shared__ float wts[32];

  // B fragments: bfrag[gt][ks], lane: col = gt*128 + w*16 + u, k = ks*32+q*8+j
  short8v bfrag[4][4];
#pragma unroll
  for (int gt = 0; gt < 4; ++gt) {
    const int col = gt * 128 + w * 16 + u;
#pragma unroll
    for (int ks = 0; ks < 4; ++ks) {
      const int k0 = ks * 32 + q * 8;
      const float4 w0 = *reinterpret_cast<const float4*>(Whh + (size_t)col * 128 + k0);
      const float4 w1 = *reinterpret_cast<const float4*>(Whh + (size_t)col * 128 + k0 + 4);
      short8v f;
      f[0] = (short)f2b(w0.x); f[1] = (short)f2b(w0.y);
      f[2] = (short)f2b(w0.z); f[3] = (short)f2b(w0.w);
      f[4] = (short)f2b(w1.x); f[5] = (short)f2b(w1.y);
      f[6] = (short)f2b(w1.z); f[7] = (short)f2b(w1.w);
      bfrag[gt][ks] = f;
    }
  }

  for (int i = tid; i < 2048; i += 512) { hbuf[0][i] = 0; hbuf[1][i] = 0; }
  if (tid < 32) wts[tid] = wtime[tid];
  const unsigned int* P32 = reinterpret_cast<const unsigned int*>(P);
  {
    const int trow0 = dir ? (Tt - 1) : 0;
    pgbuf[0][tid] = P32[((size_t)trow0 * Bb + b0 + (tid >> 8)) * 256 + (tid & 255)];
  }
  float c_st[2] = {}, ha[2] = {}, ca[2] = {};
  int cur = 0;
  __syncthreads();

  for (int s = 0; s < Tt; ++s) {
    if ((s & 7) == 0 && s) {  // flush 8 buffered output steps, coalesced
      const int k = tid >> 6, r = (tid >> 5) & 1, c4 = (tid & 31) * 4;
      const uint2 v = *reinterpret_cast<const uint2*>(&histb[(k * 2 + r) * 128 + c4]);
      *reinterpret_cast<uint2*>(&Y[((size_t)(s - 8 + k) * Bb + b0 + r) * Dp + dir * Hh + c4]) = v;
      __syncthreads();
    }
    unsigned int np = 0;
    if (s < Tt - 1) {  // prefetch next step's pre-gates (both rows, coalesced)
      const int trn = dir ? (Tt - 2 - s) : (s + 1);
      np = P32[((size_t)trn * Bb + b0 + (tid >> 8)) * 256 + (tid & 255)];
    }
    short8v afrag[4];
#pragma unroll
    for (int ks = 0; ks < 4; ++ks)
      afrag[ks] = *reinterpret_cast<const short8v*>(&hbuf[cur][(ks * 4 + q) * 128 + u * 8]);
    f32x4 gacc[4];
#pragma unroll
    for (int gt = 0; gt < 4; ++gt) {
      f32x4 acc = {0.f, 0.f, 0.f, 0.f};
#pragma unroll
      for (int ks = 0; ks < 4; ++ks)
        acc = __builtin_amdgcn_mfma_f32_16x16x32_bf16(afrag[ks], bfrag[gt][ks], acc, 0, 0, 0);
      gacc[gt] = acc;
    }
    if (lane < 16) {
      const float wt = wts[s & 31];
      const bool ce = (s & 31) == 31;
      const int colh = w * 16 + u;
#pragma unroll
      for (int r = 0; r < 2; ++r) {
        float g4[4];
#pragma unroll
        for (int gt = 0; gt < 4; ++gt) {
          const unsigned int pw = pgbuf[cur][r * 256 + gt * 64 + (colh >> 1)];
          const unsigned short pb = (colh & 1) ? (unsigned short)(pw >> 16)
                                               : (unsigned short)(pw & 0xFFFF);
          g4[gt] = gacc[gt][r] + b2f(pb);
        }
        float cs = sigf(g4[1]) * c_st[r] + sigf(g4[0]) * tanhfast(g4[2]);
        float hn = sigf(g4[3]) * tanhfast(cs);
        ha[r] += wt * hn;
        ca[r] += wt * cs;
        if (ce) { hn = ha[r]; cs = ca[r]; ha[r] = 0.f; ca[r] = 0.f; }
        c_st[r] = cs;
        const unsigned short hb = f2b(hn);
        hbuf[cur ^ 1][(colh >> 3) * 128 + r * 8 + (colh & 7)] = hb;
        histb[((s & 7) * 2 + r) * 128 + colh] = hb;
      }
    }
    if (s < Tt - 1) pgbuf[cur ^ 1][tid] = np;
    __syncthreads();
    cur ^= 1;
  }
  {  // final flush (steps 504..511)
    const int k = tid >> 6, r = (tid >> 5) & 1, c4 = (tid & 31) * 4;
    const uint2 v = *reinterpret_cast<const uint2*>(&histb[(k * 2 + r) * 128 + c4]);
    *reinterpret_cast<uint2*>(&Y[((size_t)(Tt - 8 + k) * Bb + b0 + r) * Dp + dir * Hh + c4]) = v;
  }
}

// pot[m][r] = tmp[m][:] . W_a2[r][:]   (tmp fp32)
__global__ __launch_bounds__(256) void pot_k(const float* __restrict__ tmp,
    const float* __restrict__ Wa2, float* __restrict__ pot) {
  const int tid = threadIdx.x;
  const int row = blockIdx.x * 32 + (tid >> 3);
  const int r = tid & 7;
  __shared__ float w2[8 * 129];
  for (int i = tid; i < 1024; i += 256) w2[(i >> 7) * 129 + (i & 127)] = Wa2[i];
  __syncthreads();
  float acc = 0.f;
  const float* tr = tmp + (size_t)row * 128;
#pragma unroll
  for (int k4 = 0; k4 < 32; ++k4) {
    const float4 tv = *reinterpret_cast<const float4*>(tr + k4 * 4);
    acc += tv.x * w2[r * 129 + k4 * 4 + 0];
    acc += tv.y * w2[r * 129 + k4 * 4 + 1];
    acc += tv.z * w2[r * 129 + k4 * 4 + 2];
    acc += tv.w * w2[r * 129 + k4 * 4 + 3];
  }
  pot[(size_t)row * 8 + r] = acc;
}

// masked softmax over t for one (b,r); writes Wt[b][r][t]
__global__ __launch_bounds__(256) void softmax_k(const float* __restrict__ pot,
    const int* __restrict__ length, float* __restrict__ Wt) {
  const int b = blockIdx.x >> 3, r = blockIdx.x & 7;
  const int tid = threadIdx.x;
  const int len = length[b];
  __shared__ float rbuf[4];
  const int t1 = tid, t2 = tid + 256;
  const float x1 = (t1 < len) ? pot[((size_t)t1 * Bb + b) * 8 + r] : -INFINITY;
  const float x2 = (t2 < len) ? pot[((size_t)t2 * Bb + b) * 8 + r] : -INFINITY;
  float m = fmaxf(x1, x2);
#pragma unroll
  for (int off = 32; off >= 1; off >>= 1) m = fmaxf(m, __shfl_xor(m, off));
  if ((tid & 63) == 0) rbuf[tid >> 6] = m;
  __syncthreads();
  m = fmaxf(fmaxf(rbuf[0], rbuf[1]), fmaxf(rbuf[2], rbuf[3]));
  const float e1 = (t1 < len) ? __expf(x1 - m) : 0.f;
  const float e2 = (t2 < len) ? __expf(x2 - m) : 0.f;
  float ssum = e1 + e2;
#pragma unroll
  for (int off = 32; off >= 1; off >>= 1) ssum += __shfl_xor(ssum, off);
  __syncthreads();
  if ((tid & 63) == 0) rbuf[tid >> 6] = ssum;
  __syncthreads();
  ssum = rbuf[0] + rbuf[1] + rbuf[2] + rbuf[3];
  const float inv = 1.0f / ssum;
  float* wrow = Wt + ((size_t)b * 8 + r) * Tt;
  wrow[t1] = e1 * inv;
  wrow[t2] = e2 * inv;
}

// Per-b: pooled = sum_t w[r][t]*Y[t][b][:], logits, log_softmax, gram penalty.
__global__ __launch_bounds__(256) void pool_k(const unsigned short* __restrict__ Y,
    const float* __restrict__ Wt, const float* __restrict__ Wout,
    const float* __restrict__ bout, float* __restrict__ outF,
    float* __restrict__ penpart) {
  const int b = blockIdx.x;
  const int tid = threadIdx.x;
  __shared__ float ws[8 * 513];
  __shared__ float pooled[2048];
  __shared__ float red[256];
  __shared__ float lg[8];
  for (int i = tid; i < 4096; i += 256) ws[(i >> 9) * 513 + (i & 511)] = Wt[(size_t)b * 4096 + i];
  __syncthreads();
  float acc[8] = {};
  for (int t = 0; t < Tt; ++t) {
    const float y = b2f(Y[((size_t)t * Bb + b) * Dp + tid]);
#pragma unroll
    for (int r = 0; r < 8; ++r) acc[r] += ws[r * 513 + t] * y;
  }
#pragma unroll
  for (int r = 0; r < 8; ++r) pooled[r * 256 + tid] = acc[r];
  __syncthreads();
  for (int o = 0; o < 7; ++o) {
    float p = 0.f;
    for (int j = tid; j < 2048; j += 256) p += pooled[j] * Wout[(size_t)o * 2048 + j];
    red[tid] = p;
    __syncthreads();
    for (int st = 128; st >= 1; st >>= 1) {
      if (tid < st) red[tid] += red[tid + st];
      __syncthreads();
    }
    if (tid == 0) lg[o] = red[0] + bout[o];
    __syncthreads();
  }
  if (tid == 0) {
    float mx = lg[0];
    for (int o = 1; o < 7; ++o) mx = fmaxf(mx, lg[o]);
    float ssum = 0.f;
    for (int o = 0; o < 7; ++o) ssum += __expf(lg[o] - mx);
    const float lse = mx + __logf(ssum);
    for (int o = 0; o < 7; ++o) outF[b * 7 + o] = lg[o] - lse;
  }
  for (int i = tid; i < 4096; i += 256) {
    const int rr = i >> 9, t = i & 511;
    ws[rr * 513 + t] = sqrtf(ws[rr * 513 + t]);
  }
  __syncthreads();
  float pp = 0.f;
  if (tid < 64) {
    const int rr = tid >> 3, ssi = tid & 7;
    float g = 0.f;
    for (int t = 0; t < Tt; ++t) g += ws[rr * 513 + t] * ws[ssi * 513 + t];
    const float d = g - 1.0f;
    pp = d * d;
  }
  red[tid] = pp;
  __syncthreads();
  for (int st = 128; st >= 1; st >>= 1) {
    if (tid < st) red[tid] += red[tid + st];
    __syncthreads();
  }
  if (tid == 0) penpart[b] = red[0];
}

__global__ __launch_bounds__(256) void penred_k(const float* __restrict__ penpart,
                                                float* __restrict__ outp) {
  const int tid = threadIdx.x;
  __shared__ float red[256];
  red[tid] = penpart[tid];
  __syncthreads();
  for (int st = 128; st >= 1; st >>= 1) {
    if (tid < st) red[tid] += red[tid + st];
    __syncthreads();
  }
  if (tid == 0) outp[0] = red[0];
}

} // namespace

extern "C" void kernel_launch(void* const* d_in, const int* in_sizes, int n_in,
                              void* d_out, int out_size, void* d_ws, size_t ws_size,
                              hipStream_t stream) {
  (void)in_sizes; (void)n_in; (void)out_size;
  const float* x     = (const float*)d_in[0];
  const float* W_in  = (const float*)d_in[1];
  const float* b_in  = (const float*)d_in[2];
  const float* W_ih  = (const float*)d_in[3];
  const float* b_ih  = (const float*)d_in[4];
  const float* W_hh  = (const float*)d_in[5];
  const float* b_hh  = (const float*)d_in[6];
  const float* wtime = (const float*)d_in[7];
  const float* W_a1  = (const float*)d_in[8];
  const float* b_a1  = (const float*)d_in[9];
  const float* W_a2  = (const float*)d_in[10];
  const float* W_out = (const float*)d_in[11];
  const float* b_out = (const float*)d_in[12];
  const int*   length= (const int*)d_in[13];
  float* outF = (float*)d_out;

  typedef unsigned short bf16;
  char* ws = (char*)d_ws;
  size_t off = 0;
  auto alloc = [&](size_t bytes) {
    void* p = ws + off; off += (bytes + 255) & ~(size_t)255; return p;
  };
  bf16*  act  = (bf16*)alloc((size_t)M * 256 * 2);   // activations [T*B][256], bf16
  bf16*  Pg   = (bf16*)alloc((size_t)M * 512 * 2);   // pre-gates  [T*B][512], bf16
  float* pot  = (float*)alloc((size_t)M * 8 * 4);
  float* Wt   = (float*)alloc((size_t)Bb * 8 * Tt * 4);
  float* penp = (float*)alloc(Bb * 4);
  float* tmpA = (float*)Pg;  // attention tanh activations [M][128] fp32, aliases dead Pg

  if (ws_size < off) return;  // workspace too small: clean absmax-fail, not a crash

  const dim3 blk(256);
  // input layer: rows (t,b) <- x[b][t][:]
  mgemm_k<128, 1, 0, float, bf16><<<dim3(2, M / 128), blk, 0, stream>>>(x, W_in, b_in, nullptr, act, 256);
  // layer 0
  mgemm_k<256, 0, 0, bf16, bf16><<<dim3(4, M / 128), blk, 0, stream>>>(act, W_ih, b_ih, b_hh, Pg, 512);
  lstm_k<<<dim3(256), dim3(512), 0, stream>>>(Pg, W_hh, wtime, act);
  // layer 1 (shared weights)
  mgemm_k<256, 0, 0, bf16, bf16><<<dim3(4, M / 128), blk, 0, stream>>>(act, W_ih, b_ih, b_hh, Pg, 512);
  lstm_k<<<dim3(256), dim3(512), 0, stream>>>(Pg, W_hh, wtime, act);
  // attention
  mgemm_k<256, 0, 1, bf16, float><<<dim3(1, M / 128), blk, 0, stream>>>(act, W_a1, b_a1, nullptr, tmpA, 128);
  pot_k<<<dim3(M / 32), blk, 0, stream>>>(tmpA, W_a2, pot);
  softmax_k<<<dim3(Bb * 8), blk, 0, stream>>>(pot, length, Wt);
  pool_k<<<dim3(Bb), blk, 0, stream>>>(act, Wt, W_out, b_out, outF, penp);
  penred_k<<<dim3(1), blk, 0, stream>>>(penp, outF + Bb * 7);
}

// Round 6
// 1288.868 us; speedup vs baseline: 2.7090x; 1.2568x over previous
//
#include <hip/hip_runtime.h>
#include <math.h>

namespace {

constexpr int Bb = 256, Tt = 512, Dp = 256, Hh = 128, G = 512;
constexpr int M = Tt * Bb; // 131072 rows (t-major: row = t*B + b)

typedef __attribute__((ext_vector_type(8))) short short8v;
typedef __attribute__((ext_vector_type(4))) float f32x4;

// Native-rate sigmoid/tanh: v_rcp_f32 instead of IEEE divide chains.
// rcp rel-err ~2.5e-7 << bf16 quantization (4e-3).
__device__ __forceinline__ float sigf(float x) {
  return __builtin_amdgcn_rcpf(1.0f + __expf(-x));
}
__device__ __forceinline__ float tanhfast(float x) {
  // tanh(x) = 1 - 2/(exp(2x)+1); exp->inf => rcp->0 => 1; exp->0 => -1. No clamps.
  const float e = __expf(2.0f * x);
  return 1.0f - 2.0f * __builtin_amdgcn_rcpf(e + 1.0f);
}
__device__ __forceinline__ float b2f(unsigned short u) {
  return __uint_as_float((unsigned int)u << 16);
}
__device__ __forceinline__ unsigned short f2b(float f) {
  unsigned int u = __float_as_uint(f);
  u += 0x7FFFu + ((u >> 16) & 1u);   // round-to-nearest-even
  return (unsigned short)(u >> 16);
}
__device__ __forceinline__ unsigned int pack2(float a, float b) {
  return (unsigned int)f2b(a) | ((unsigned int)f2b(b) << 16);
}

// MFMA GEMM: C[m][n] = sum_k A[arow(m)][k]*W[n][k] + bias1[n] (+bias2[n]); opt tanh.
// 128x128 tile, 4 waves (64x64 quadrant each), BK=64 double-buffered LDS.
template<int K, int SWAP, int TANH, typename AT, typename CT>
__global__ __launch_bounds__(256) void mgemm_k(const AT* __restrict__ A,
    const float* __restrict__ W, const float* __restrict__ bias1,
    const float* __restrict__ bias2, CT* __restrict__ C, int N) {
  constexpr int NK = K / 64;
  __shared__ unsigned short aLds[2][8192];  // [buf][(kc*8+mf)*64+lane][8]
  __shared__ unsigned short wLds[2][8192];
  const int tid = threadIdx.x;
  const int lane = tid & 63;
  const int wave = tid >> 6;
  const int wm = wave >> 1, wn = wave & 1;
  const int m0 = blockIdx.y * 128, n0 = blockIdx.x * 128;

  const int srow = tid >> 1;   // 0..127: A-tile row / W-tile col
  const int skc = tid & 1;     // k-half of the 64-wide K step
  int am;
  if constexpr (SWAP) { const int m = m0 + srow; am = (m & 255) * Tt + (m >> 8); }
  else am = m0 + srow;

  uint4 ra[4];
  float4 raf[4][2];
  float4 rw[4][2];

  auto loadA = [&](int kb) {
    const int kbase = kb * 64 + skc * 32;
    if constexpr (sizeof(AT) == 2) {
      const unsigned short* src = reinterpret_cast<const unsigned short*>(A) + (size_t)am * K + kbase;
#pragma unroll
      for (int q = 0; q < 4; ++q) ra[q] = *reinterpret_cast<const uint4*>(src + q * 8);
    } else {
      const float* src = reinterpret_cast<const float*>(A) + (size_t)am * K + kbase;
#pragma unroll
      for (int q = 0; q < 4; ++q) {
        raf[q][0] = *reinterpret_cast<const float4*>(src + q * 8);
        raf[q][1] = *reinterpret_cast<const float4*>(src + q * 8 + 4);
      }
    }
  };
  auto loadW = [&](int kb) {
    const int kbase = kb * 64 + skc * 32;
    const float* src = W + (size_t)(n0 + srow) * K + kbase;
#pragma unroll
    for (int q = 0; q < 4; ++q) {
      rw[q][0] = *reinterpret_cast<const float4*>(src + q * 8);
      rw[q][1] = *reinterpret_cast<const float4*>(src + q * 8 + 4);
    }
  };
  auto writeS = [&](int buf) {
    const int base = (skc * 8 + (srow >> 4)) * 64 + (srow & 15);
#pragma unroll
    for (int q = 0; q < 4; ++q) {
      const int slot = base + q * 16;
      if constexpr (sizeof(AT) == 2) {
        *reinterpret_cast<uint4*>(&aLds[buf][slot * 8]) = ra[q];
      } else {
        uint4 p;
        p.x = pack2(raf[q][0].x, raf[q][0].y); p.y = pack2(raf[q][0].z, raf[q][0].w);
        p.z = pack2(raf[q][1].x, raf[q][1].y); p.w = pack2(raf[q][1].z, raf[q][1].w);
        *reinterpret_cast<uint4*>(&aLds[buf][slot * 8]) = p;
      }
      uint4 pw;
      pw.x = pack2(rw[q][0].x, rw[q][0].y); pw.y = pack2(rw[q][0].z, rw[q][0].w);
      pw.z = pack2(rw[q][1].x, rw[q][1].y); pw.w = pack2(rw[q][1].z, rw[q][1].w);
      *reinterpret_cast<uint4*>(&wLds[buf][slot * 8]) = pw;
    }
  };

  f32x4 acc[4][4] = {};
  int cur = 0;
  loadA(0); loadW(0); writeS(0);
  __syncthreads();
  for (int kb = 0; kb < NK; ++kb) {
    const bool more = (kb + 1 < NK);
    if (more) { loadA(kb + 1); loadW(kb + 1); }
#pragma unroll
    for (int kc = 0; kc < 2; ++kc) {
      short8v af[4], bfr[4];
#pragma unroll
      for (int i = 0; i < 4; ++i)
        af[i] = *reinterpret_cast<const short8v*>(
            &aLds[cur][((kc * 8 + wm * 4 + i) * 64 + lane) * 8]);
#pragma unroll
      for (int j = 0; j < 4; ++j)
        bfr[j] = *reinterpret_cast<const short8v*>(
            &wLds[cur][((kc * 8 + wn * 4 + j) * 64 + lane) * 8]);
#pragma unroll
      for (int i = 0; i < 4; ++i)
#pragma unroll
        for (int j = 0; j < 4; ++j)
          acc[i][j] = __builtin_amdgcn_mfma_f32_16x16x32_bf16(af[i], bfr[j], acc[i][j], 0, 0, 0);
    }
    if (more) writeS(cur ^ 1);
    __syncthreads();
    cur ^= 1;
  }
#pragma unroll
  for (int j = 0; j < 4; ++j) {
    const int gn = n0 + wn * 64 + j * 16 + (lane & 15);
    float bv = bias1[gn];
    if (bias2) bv += bias2[gn];
#pragma unroll
    for (int i = 0; i < 4; ++i) {
      const int gmb = m0 + wm * 64 + i * 16 + ((lane >> 4) << 2);
#pragma unroll
      for (int r = 0; r < 4; ++r) {
        float v = acc[i][j][r] + bv;
        if (TANH) v = tanhfast(v);
        const size_t oidx = (size_t)(gmb + r) * N + gn;
        if constexpr (sizeof(CT) == 2) C[oidx] = f2b(v); else C[oidx] = v;
      }
    }
  }
}

// MFMA bidirectional chunked LSTM, 8 waves (2/SIMD for latency hiding).
// 256 blocks (dir = bid>>7, batch pair b0=(bid&127)*2), 512 threads.
// Wave w owns gate cols {gt*128 + w*16 + u}, gt=i,f,g,o; 16 MFMAs/step.
__global__ __launch_bounds__(512, 2) void lstm_k(const unsigned short* __restrict__ P,
    const float* __restrict__ Whh, const float* __restrict__ wtime,
    unsigned short* __restrict__ Y) {
  const int tid = threadIdx.x;
  const int lane = tid & 63;
  const int w = tid >> 6;        // wave 0..7
  const int u = lane & 15;
  const int q = lane >> 4;
  const int dir = blockIdx.x >> 7;
  const int b0 = (blockIdx.x & 127) * 2;

  __shared__ unsigned short hbuf[2][2048];   // [buf][koct16][row16][8]
  __shared__ unsigned int pgbuf[2][512];     // [buf][row*256 + word]
  __shared__ unsigned short histb[2048];     // [step&7][row2][col128]
  __shared__ float wts[32];

  // B fragments: bfrag[gt][ks], lane: col = gt*128 + w*16 + u, k = ks*32+q*8+j
  short8v bfrag[4][4];
#pragma unroll
  for (int gt = 0; gt < 4; ++gt) {
    const int col = gt * 128 + w * 16 + u;
#pragma unroll
    for (int ks = 0; ks < 4; ++ks) {
      const int k0 = ks * 32 + q * 8;
      const float4 w0 = *reinterpret_cast<const float4*>(Whh + (size_t)col * 128 + k0);
      const float4 w1 = *reinterpret_cast<const float4*>(Whh + (size_t)col * 128 + k0 + 4);
      short8v f;
      f[0] = (short)f2b(w0.x); f[1] = (short)f2b(w0.y);
      f[2] = (short)f2b(w0.z); f[3] = (short)f2b(w0.w);
      f[4] = (short)f2b(w1.x); f[5] = (short)f2b(w1.y);
      f[6] = (short)f2b(w1.z); f[7] = (short)f2b(w1.w);
      bfrag[gt][ks] = f;
    }
  }

  for (int i = tid; i < 2048; i += 512) { hbuf[0][i] = 0; hbuf[1][i] = 0; }
  if (tid < 32) wts[tid] = wtime[tid];
  const unsigned int* P32 = reinterpret_cast<const unsigned int*>(P);
  {
    const int trow0 = dir ? (Tt - 1) : 0;
    pgbuf[0][tid] = P32[((size_t)trow0 * Bb + b0 + (tid >> 8)) * 256 + (tid & 255)];
  }
  float c_st[2] = {}, ha[2] = {}, ca[2] = {};
  int cur = 0;
  __syncthreads();

  for (int s = 0; s < Tt; ++s) {
    if ((s & 7) == 0 && s) {  // flush 8 buffered output steps, coalesced
      const int k = tid >> 6, r = (tid >> 5) & 1, c4 = (tid & 31) * 4;
      const uint2 v = *reinterpret_cast<const uint2*>(&histb[(k * 2 + r) * 128 + c4]);
      *reinterpret_cast<uint2*>(&Y[((size_t)(s - 8 + k) * Bb + b0 + r) * Dp + dir * Hh + c4]) = v;
      __syncthreads();
    }
    unsigned int np = 0;
    if (s < Tt - 1) {  // prefetch next step's pre-gates (both rows, coalesced)
      const int trn = dir ? (Tt - 2 - s) : (s + 1);
      np = P32[((size_t)trn * Bb + b0 + (tid >> 8)) * 256 + (tid & 255)];
    }
    short8v afrag[4];
#pragma unroll
    for (int ks = 0; ks < 4; ++ks)
      afrag[ks] = *reinterpret_cast<const short8v*>(&hbuf[cur][(ks * 4 + q) * 128 + u * 8]);
    f32x4 gacc[4];
#pragma unroll
    for (int gt = 0; gt < 4; ++gt) {
      f32x4 acc = {0.f, 0.f, 0.f, 0.f};
#pragma unroll
      for (int ks = 0; ks < 4; ++ks)
        acc = __builtin_amdgcn_mfma_f32_16x16x32_bf16(afrag[ks], bfrag[gt][ks], acc, 0, 0, 0);
      gacc[gt] = acc;
    }
    if (lane < 16) {
      const float wt = wts[s & 31];
      const bool ce = (s & 31) == 31;
      const int colh = w * 16 + u;
#pragma unroll
      for (int r = 0; r < 2; ++r) {
        float g4[4];
#pragma unroll
        for (int gt = 0; gt < 4; ++gt) {
          const unsigned int pw = pgbuf[cur][r * 256 + gt * 64 + (colh >> 1)];
          const unsigned short pb = (colh & 1) ? (unsigned short)(pw >> 16)
                                               : (unsigned short)(pw & 0xFFFF);
          g4[gt] = gacc[gt][r] + b2f(pb);
        }
        float cs = sigf(g4[1]) * c_st[r] + sigf(g4[0]) * tanhfast(g4[2]);
        float hn = sigf(g4[3]) * tanhfast(cs);
        ha[r] += wt * hn;
        ca[r] += wt * cs;
        if (ce) { hn = ha[r]; cs = ca[r]; ha[r] = 0.f; ca[r] = 0.f; }
        c_st[r] = cs;
        const unsigned short hb = f2b(hn);
        hbuf[cur ^ 1][(colh >> 3) * 128 + r * 8 + (colh & 7)] = hb;
        histb[((s & 7) * 2 + r) * 128 + colh] = hb;
      }
    }
    if (s < Tt - 1) pgbuf[cur ^ 1][tid] = np;
    __syncthreads();
    cur ^= 1;
  }
  {  // final flush (steps 504..511)
    const int k = tid >> 6, r = (tid >> 5) & 1, c4 = (tid & 31) * 4;
    const uint2 v = *reinterpret_cast<const uint2*>(&histb[(k * 2 + r) * 128 + c4]);
    *reinterpret_cast<uint2*>(&Y[((size_t)(Tt - 8 + k) * Bb + b0 + r) * Dp + dir * Hh + c4]) = v;
  }
}

// pot[m][r] = tmp[m][:] . W_a2[r][:]   (tmp fp32)
__global__ __launch_bounds__(256) void pot_k(const float* __restrict__ tmp,
    const float* __restrict__ Wa2, float* __restrict__ pot) {
  const int tid = threadIdx.x;
  const int row = blockIdx.x * 32 + (tid >> 3);
  const int r = tid & 7;
  __shared__ float w2[8 * 129];
  for (int i = tid; i < 1024; i += 256) w2[(i >> 7) * 129 + (i & 127)] = Wa2[i];
  __syncthreads();
  float acc = 0.f;
  const float* tr = tmp + (size_t)row * 128;
#pragma unroll
  for (int k4 = 0; k4 < 32; ++k4) {
    const float4 tv = *reinterpret_cast<const float4*>(tr + k4 * 4);
    acc += tv.x * w2[r * 129 + k4 * 4 + 0];
    acc += tv.y * w2[r * 129 + k4 * 4 + 1];
    acc += tv.z * w2[r * 129 + k4 * 4 + 2];
    acc += tv.w * w2[r * 129 + k4 * 4 + 3];
  }
  pot[(size_t)row * 8 + r] = acc;
}

// masked softmax over t for one (b,r); writes Wt[b][r][t]
__global__ __launch_bounds__(256) void softmax_k(const float* __restrict__ pot,
    const int* __restrict__ length, float* __restrict__ Wt) {
  const int b = blockIdx.x >> 3, r = blockIdx.x & 7;
  const int tid = threadIdx.x;
  const int len = length[b];
  __shared__ float rbuf[4];
  const int t1 = tid, t2 = tid + 256;
  const float x1 = (t1 < len) ? pot[((size_t)t1 * Bb + b) * 8 + r] : -INFINITY;
  const float x2 = (t2 < len) ? pot[((size_t)t2 * Bb + b) * 8 + r] : -INFINITY;
  float m = fmaxf(x1, x2);
#pragma unroll
  for (int off = 32; off >= 1; off >>= 1) m = fmaxf(m, __shfl_xor(m, off));
  if ((tid & 63) == 0) rbuf[tid >> 6] = m;
  __syncthreads();
  m = fmaxf(fmaxf(rbuf[0], rbuf[1]), fmaxf(rbuf[2], rbuf[3]));
  const float e1 = (t1 < len) ? __expf(x1 - m) : 0.f;
  const float e2 = (t2 < len) ? __expf(x2 - m) : 0.f;
  float ssum = e1 + e2;
#pragma unroll
  for (int off = 32; off >= 1; off >>= 1) ssum += __shfl_xor(ssum, off);
  __syncthreads();
  if ((tid & 63) == 0) rbuf[tid >> 6] = ssum;
  __syncthreads();
  ssum = rbuf[0] + rbuf[1] + rbuf[2] + rbuf[3];
  const float inv = 1.0f / ssum;
  float* wrow = Wt + ((size_t)b * 8 + r) * Tt;
  wrow[t1] = e1 * inv;
  wrow[t2] = e2 * inv;
}

// Per-b: pooled = sum_t w[r][t]*Y[t][b][:], logits, log_softmax, gram penalty.
__global__ __launch_bounds__(256) void pool_k(const unsigned short* __restrict__ Y,
    const float* __restrict__ Wt, const float* __restrict__ Wout,
    const float* __restrict__ bout, float* __restrict__ outF,
    float* __restrict__ penpart) {
  const int b = blockIdx.x;
  const int tid = threadIdx.x;
  __shared__ float ws[8 * 513];
  __shared__ float pooled[2048];
  __shared__ float red[256];
  __shared__ float lg[8];
  for (int i = tid; i < 4096; i += 256) ws[(i >> 9) * 513 + (i & 511)] = Wt[(size_t)b * 4096 + i];
  __syncthreads();
  float acc[8] = {};
  for (int t = 0; t < Tt; ++t) {
    const float y = b2f(Y[((size_t)t * Bb + b) * Dp + tid]);
#pragma unroll
    for (int r = 0; r < 8; ++r) acc[r] += ws[r * 513 + t] * y;
  }
#pragma unroll
  for (int r = 0; r < 8; ++r) pooled[r * 256 + tid] = acc[r];
  __syncthreads();
  for (int o = 0; o < 7; ++o) {
    float p = 0.f;
    for (int j = tid; j < 2048; j += 256) p += pooled[j] * Wout[(size_t)o * 2048 + j];
    red[tid] = p;
    __syncthreads();
    for (int st = 128; st >= 1; st >>= 1) {
      if (tid < st) red[tid] += red[tid + st];
      __syncthreads();
    }
    if (tid == 0) lg[o] = red[0] + bout[o];
    __syncthreads();
  }
  if (tid == 0) {
    float mx = lg[0];
    for (int o = 1; o < 7; ++o) mx = fmaxf(mx, lg[o]);
    float ssum = 0.f;
    for (int o = 0; o < 7; ++o) ssum += __expf(lg[o] - mx);
    const float lse = mx + __logf(ssum);
    for (int o = 0; o < 7; ++o) outF[b * 7 + o] = lg[o] - lse;
  }
  for (int i = tid; i < 4096; i += 256) {
    const int rr = i >> 9, t = i & 511;
    ws[rr * 513 + t] = sqrtf(ws[rr * 513 + t]);
  }
  __syncthreads();
  float pp = 0.f;
  if (tid < 64) {
    const int rr = tid >> 3, ssi = tid & 7;
    float g = 0.f;
    for (int t = 0; t < Tt; ++t) g += ws[rr * 513 + t] * ws[ssi * 513 + t];
    const float d = g - 1.0f;
    pp = d * d;
  }
  red[tid] = pp;
  __syncthreads();
  for (int st = 128; st >= 1; st >>= 1) {
    if (tid < st) red[tid] += red[tid + st];
    __syncthreads();
  }
  if (tid == 0) penpart[b] = red[0];
}

__global__ __launch_bounds__(256) void penred_k(const float* __restrict__ penpart,
                                                float* __restrict__ outp) {
  const int tid = threadIdx.x;
  __shared__ float red[256];
  red[tid] = penpart[tid];
  __syncthreads();
  for (int st = 128; st >= 1; st >>= 1) {
    if (tid < st) red[tid] += red[tid + st];
    __syncthreads();
  }
  if (tid == 0) outp[0] = red[0];
}

} // namespace

extern "C" void kernel_launch(void* const* d_in, const int* in_sizes, int n_in,
                              void* d_out, int out_size, void* d_ws, size_t ws_size,
                              hipStream_t stream) {
  (void)in_sizes; (void)n_in; (void)out_size;
  const float* x     = (const float*)d_in[0];
  const float* W_in  = (const float*)d_in[1];
  const float* b_in  = (const float*)d_in[2];
  const float* W_ih  = (const float*)d_in[3];
  const float* b_ih  = (const float*)d_in[4];
  const float* W_hh  = (const float*)d_in[5];
  const float* b_hh  = (const float*)d_in[6];
  const float* wtime = (const float*)d_in[7];
  const float* W_a1  = (const float*)d_in[8];
  const float* b_a1  = (const float*)d_in[9];
  const float* W_a2  = (const float*)d_in[10];
  const float* W_out = (const float*)d_in[11];
  const float* b_out = (const float*)d_in[12];
  const int*   length= (const int*)d_in[13];
  float* outF = (float*)d_out;

  typedef unsigned short bf16;
  char* ws = (char*)d_ws;
  size_t off = 0;
  auto alloc = [&](size_t bytes) {
    void* p = ws + off; off += (bytes + 255) & ~(size_t)255; return p;
  };
  bf16*  act  = (bf16*)alloc((size_t)M * 256 * 2);   // activations [T*B][256], bf16
  bf16*  Pg   = (bf16*)alloc((size_t)M * 512 * 2);   // pre-gates  [T*B][512], bf16
  float* pot  = (float*)alloc((size_t)M * 8 * 4);
  float* Wt   = (float*)alloc((size_t)Bb * 8 * Tt * 4);
  float* penp = (float*)alloc(Bb * 4);
  float* tmpA = (float*)Pg;  // attention tanh activations [M][128] fp32, aliases dead Pg

  if (ws_size < off) return;  // workspace too small: clean absmax-fail, not a crash

  const dim3 blk(256);
  // input layer: rows (t,b) <- x[b][t][:]
  mgemm_k<128, 1, 0, float, bf16><<<dim3(2, M / 128), blk, 0, stream>>>(x, W_in, b_in, nullptr, act, 256);
  // layer 0
  mgemm_k<256, 0, 0, bf16, bf16><<<dim3(4, M / 128), blk, 0, stream>>>(act, W_ih, b_ih, b_hh, Pg, 512);
  lstm_k<<<dim3(256), dim3(512), 0, stream>>>(Pg, W_hh, wtime, act);
  // layer 1 (shared weights)
  mgemm_k<256, 0, 0, bf16, bf16><<<dim3(4, M / 128), blk, 0, stream>>>(act, W_ih, b_ih, b_hh, Pg, 512);
  lstm_k<<<dim3(256), dim3(512), 0, stream>>>(Pg, W_hh, wtime, act);
  // attention
  mgemm_k<256, 0, 1, bf16, float><<<dim3(1, M / 128), blk, 0, stream>>>(act, W_a1, b_a1, nullptr, tmpA, 128);
  pot_k<<<dim3(M / 32), blk, 0, stream>>>(tmpA, W_a2, pot);
  softmax_k<<<dim3(Bb * 8), blk, 0, stream>>>(pot, length, Wt);
  pool_k<<<dim3(Bb), blk, 0, stream>>>(act, Wt, W_out, b_out, outF, penp);
  penred_k<<<dim3(1), blk, 0, stream>>>(penp, outF + Bb * 7);
}

// Round 7
// 1134.513 us; speedup vs baseline: 3.0776x; 1.1361x over previous
//
#include <hip/hip_runtime.h>
#include <math.h>

namespace {

constexpr int Bb = 256, Tt = 512, Dp = 256, Hh = 128, G = 512;
constexpr int M = Tt * Bb; // 131072 rows (t-major: row = t*B + b)

typedef __attribute__((ext_vector_type(8))) short short8v;
typedef __attribute__((ext_vector_type(4))) float f32x4;

// Native-rate sigmoid/tanh: v_rcp_f32 instead of IEEE divide chains.
__device__ __forceinline__ float sigf(float x) {
  return __builtin_amdgcn_rcpf(1.0f + __expf(-x));
}
__device__ __forceinline__ float tanhfast(float x) {
  const float e = __expf(2.0f * x);
  return 1.0f - 2.0f * __builtin_amdgcn_rcpf(e + 1.0f);
}
__device__ __forceinline__ float b2f(unsigned short u) {
  return __uint_as_float((unsigned int)u << 16);
}
__device__ __forceinline__ unsigned short f2b(float f) {
  unsigned int u = __float_as_uint(f);
  u += 0x7FFFu + ((u >> 16) & 1u);   // round-to-nearest-even
  return (unsigned short)(u >> 16);
}
__device__ __forceinline__ unsigned int pack2(float a, float b) {
  return (unsigned int)f2b(a) | ((unsigned int)f2b(b) << 16);
}

// MFMA GEMM: C[m][n] = sum_k A[arow(m)][k]*W[n][k] + bias1[n] (+bias2[n]); opt tanh.
// 128x128 tile, 4 waves (64x64 quadrant each), BK=64 double-buffered LDS.
template<int K, int SWAP, int TANH, typename AT, typename CT>
__global__ __launch_bounds__(256) void mgemm_k(const AT* __restrict__ A,
    const float* __restrict__ W, const float* __restrict__ bias1,
    const float* __restrict__ bias2, CT* __restrict__ C, int N) {
  constexpr int NK = K / 64;
  __shared__ unsigned short aLds[2][8192];  // [buf][(kc*8+mf)*64+lane][8]
  __shared__ unsigned short wLds[2][8192];
  const int tid = threadIdx.x;
  const int lane = tid & 63;
  const int wave = tid >> 6;
  const int wm = wave >> 1, wn = wave & 1;
  const int m0 = blockIdx.y * 128, n0 = blockIdx.x * 128;

  const int srow = tid >> 1;   // 0..127: A-tile row / W-tile col
  const int skc = tid & 1;     // k-half of the 64-wide K step
  int am;
  if constexpr (SWAP) { const int m = m0 + srow; am = (m & 255) * Tt + (m >> 8); }
  else am = m0 + srow;

  uint4 ra[4];
  float4 raf[4][2];
  float4 rw[4][2];

  auto loadA = [&](int kb) {
    const int kbase = kb * 64 + skc * 32;
    if constexpr (sizeof(AT) == 2) {
      const unsigned short* src = reinterpret_cast<const unsigned short*>(A) + (size_t)am * K + kbase;
#pragma unroll
      for (int q = 0; q < 4; ++q) ra[q] = *reinterpret_cast<const uint4*>(src + q * 8);
    } else {
      const float* src = reinterpret_cast<const float*>(A) + (size_t)am * K + kbase;
#pragma unroll
      for (int q = 0; q < 4; ++q) {
        raf[q][0] = *reinterpret_cast<const float4*>(src + q * 8);
        raf[q][1] = *reinterpret_cast<const float4*>(src + q * 8 + 4);
      }
    }
  };
  auto loadW = [&](int kb) {
    const int kbase = kb * 64 + skc * 32;
    const float* src = W + (size_t)(n0 + srow) * K + kbase;
#pragma unroll
    for (int q = 0; q < 4; ++q) {
      rw[q][0] = *reinterpret_cast<const float4*>(src + q * 8);
      rw[q][1] = *reinterpret_cast<const float4*>(src + q * 8 + 4);
    }
  };
  auto writeS = [&](int buf) {
    const int base = (skc * 8 + (srow >> 4)) * 64 + (srow & 15);
#pragma unroll
    for (int q = 0; q < 4; ++q) {
      const int slot = base + q * 16;
      if constexpr (sizeof(AT) == 2) {
        *reinterpret_cast<uint4*>(&aLds[buf][slot * 8]) = ra[q];
      } else {
        uint4 p;
        p.x = pack2(raf[q][0].x, raf[q][0].y); p.y = pack2(raf[q][0].z, raf[q][0].w);
        p.z = pack2(raf[q][1].x, raf[q][1].y); p.w = pack2(raf[q][1].z, raf[q][1].w);
        *reinterpret_cast<uint4*>(&aLds[buf][slot * 8]) = p;
      }
      uint4 pw;
      pw.x = pack2(rw[q][0].x, rw[q][0].y); pw.y = pack2(rw[q][0].z, rw[q][0].w);
      pw.z = pack2(rw[q][1].x, rw[q][1].y); pw.w = pack2(rw[q][1].z, rw[q][1].w);
      *reinterpret_cast<uint4*>(&wLds[buf][slot * 8]) = pw;
    }
  };

  f32x4 acc[4][4] = {};
  int cur = 0;
  loadA(0); loadW(0); writeS(0);
  __syncthreads();
  for (int kb = 0; kb < NK; ++kb) {
    const bool more = (kb + 1 < NK);
    if (more) { loadA(kb + 1); loadW(kb + 1); }
#pragma unroll
    for (int kc = 0; kc < 2; ++kc) {
      short8v af[4], bfr[4];
#pragma unroll
      for (int i = 0; i < 4; ++i)
        af[i] = *reinterpret_cast<const short8v*>(
            &aLds[cur][((kc * 8 + wm * 4 + i) * 64 + lane) * 8]);
#pragma unroll
      for (int j = 0; j < 4; ++j)
        bfr[j] = *reinterpret_cast<const short8v*>(
            &wLds[cur][((kc * 8 + wn * 4 + j) * 64 + lane) * 8]);
#pragma unroll
      for (int i = 0; i < 4; ++i)
#pragma unroll
        for (int j = 0; j < 4; ++j)
          acc[i][j] = __builtin_amdgcn_mfma_f32_16x16x32_bf16(af[i], bfr[j], acc[i][j], 0, 0, 0);
    }
    if (more) writeS(cur ^ 1);
    __syncthreads();
    cur ^= 1;
  }
#pragma unroll
  for (int j = 0; j < 4; ++j) {
    const int gn = n0 + wn * 64 + j * 16 + (lane & 15);
    float bv = bias1[gn];
    if (bias2) bv += bias2[gn];
#pragma unroll
    for (int i = 0; i < 4; ++i) {
      const int gmb = m0 + wm * 64 + i * 16 + ((lane >> 4) << 2);
#pragma unroll
      for (int r = 0; r < 4; ++r) {
        float v = acc[i][j][r] + bv;
        if (TANH) v = tanhfast(v);
        const size_t oidx = (size_t)(gmb + r) * N + gn;
        if constexpr (sizeof(CT) == 2) C[oidx] = f2b(v); else C[oidx] = v;
      }
    }
  }
}

// MFMA bidirectional chunked LSTM, 8 waves, role-split elementwise.
// 256 blocks (dir = bid>>7, batch pair b0=(bid&127)*2), 512 threads.
// Phase 1 (all 8 waves): 16 MFMAs each for wave-owned gate cols; gacc -> gbuf.
// Phase 2: waves 0-3 = one h-value per lane (trans chains at full lane util);
//          waves 4-7 = pre-gate prefetch LDS write + Y history flush.
__global__ __launch_bounds__(512, 2) void lstm_k(const unsigned short* __restrict__ P,
    const float* __restrict__ Whh, const float* __restrict__ wtime,
    unsigned short* __restrict__ Y) {
  const int tid = threadIdx.x;
  const int lane = tid & 63;
  const int w = tid >> 6;        // wave 0..7
  const int u = lane & 15;
  const int q = lane >> 4;
  const int dir = blockIdx.x >> 7;
  const int b0 = (blockIdx.x & 127) * 2;

  __shared__ unsigned short hbuf[2][2048];   // [buf][koct16][row16][8]
  __shared__ unsigned int pgbuf[2][512];     // [buf][row*256 + word]
  __shared__ float gbuf[1024];               // [gt*2+row][col128] f32 gates
  __shared__ unsigned short histb[4096];     // [slot16][row2][col128]
  __shared__ float wts[32];

  // B fragments: bfrag[gt][ks], lane: col = gt*128 + w*16 + u, k = ks*32+q*8+j
  short8v bfrag[4][4];
#pragma unroll
  for (int gt = 0; gt < 4; ++gt) {
    const int col = gt * 128 + w * 16 + u;
#pragma unroll
    for (int ks = 0; ks < 4; ++ks) {
      const int k0 = ks * 32 + q * 8;
      const float4 w0 = *reinterpret_cast<const float4*>(Whh + (size_t)col * 128 + k0);
      const float4 w1 = *reinterpret_cast<const float4*>(Whh + (size_t)col * 128 + k0 + 4);
      short8v f;
      f[0] = (short)f2b(w0.x); f[1] = (short)f2b(w0.y);
      f[2] = (short)f2b(w0.z); f[3] = (short)f2b(w0.w);
      f[4] = (short)f2b(w1.x); f[5] = (short)f2b(w1.y);
      f[6] = (short)f2b(w1.z); f[7] = (short)f2b(w1.w);
      bfrag[gt][ks] = f;
    }
  }

  for (int i = tid; i < 2048; i += 512) { hbuf[0][i] = 0; hbuf[1][i] = 0; }
  if (tid < 32) wts[tid] = wtime[tid];
  const unsigned int* P32 = reinterpret_cast<const unsigned int*>(P);
  {
    const int trow0 = dir ? (Tt - 1) : 0;
    pgbuf[0][tid] = P32[((size_t)trow0 * Bb + b0 + (tid >> 8)) * 256 + (tid & 255)];
  }
  // per-thread recurrent state: owner thread tid<256 -> (r=tid>>7, colh=tid&127)
  float c_st = 0.f, ha = 0.f, ca = 0.f;
  int cur = 0;
  __syncthreads();

  for (int s = 0; s < Tt; ++s) {
    // waves 4-7: issue next step's pre-gate loads early (latency hides under MFMA)
    unsigned int np0 = 0, np1 = 0;
    if (tid >= 256 && s < Tt - 1) {
      const int trn = dir ? (Tt - 2 - s) : (s + 1);
      const int j = tid - 256;
      np0 = P32[((size_t)trn * Bb + b0) * 256 + j];
      np1 = P32[((size_t)trn * Bb + b0 + 1) * 256 + j];
    }
    // all waves: A fragments from h, 16 MFMAs
    short8v afrag[4];
#pragma unroll
    for (int ks = 0; ks < 4; ++ks)
      afrag[ks] = *reinterpret_cast<const short8v*>(&hbuf[cur][(ks * 4 + q) * 128 + u * 8]);
    f32x4 gacc[4];
#pragma unroll
    for (int gt = 0; gt < 4; ++gt) {
      f32x4 acc = {0.f, 0.f, 0.f, 0.f};
#pragma unroll
      for (int ks = 0; ks < 4; ++ks)
        acc = __builtin_amdgcn_mfma_f32_16x16x32_bf16(afrag[ks], bfrag[gt][ks], acc, 0, 0, 0);
      gacc[gt] = acc;
    }
    if (lane < 16) {  // publish valid C rows (0,1) to gbuf
#pragma unroll
      for (int gt = 0; gt < 4; ++gt) {
        gbuf[(gt * 2 + 0) * 128 + w * 16 + u] = gacc[gt][0];
        gbuf[(gt * 2 + 1) * 128 + w * 16 + u] = gacc[gt][1];
      }
    }
    __syncthreads();  // gbuf ready

    if (tid < 256) {  // waves 0-3: one h per lane
      const int r = tid >> 7, colh = tid & 127;
      float g4[4];
#pragma unroll
      for (int gt = 0; gt < 4; ++gt) {
        const unsigned int pw = pgbuf[cur][r * 256 + gt * 64 + (colh >> 1)];
        const unsigned short pb = (colh & 1) ? (unsigned short)(pw >> 16)
                                             : (unsigned short)(pw & 0xFFFF);
        g4[gt] = gbuf[(gt * 2 + r) * 128 + colh] + b2f(pb);
      }
      float cs = sigf(g4[1]) * c_st + sigf(g4[0]) * tanhfast(g4[2]);
      float hn = sigf(g4[3]) * tanhfast(cs);
      const float wt = wts[s & 31];
      ha += wt * hn;
      ca += wt * cs;
      if ((s & 31) == 31) { hn = ha; cs = ca; ha = 0.f; ca = 0.f; }
      c_st = cs;
      const unsigned short hb = f2b(hn);
      hbuf[cur ^ 1][(colh >> 3) * 128 + r * 8 + (colh & 7)] = hb;
      histb[((s & 15) * 2 + r) * 128 + colh] = hb;
    } else {  // waves 4-7: pgbuf write + Y flush (16-slot histb avoids collision)
      const int j = tid - 256;
      if (s < Tt - 1) {
        pgbuf[cur ^ 1][j] = np0;
        pgbuf[cur ^ 1][256 + j] = np1;
      }
      if ((s & 7) == 0 && s) {
        const int st8 = j >> 5, r = (j >> 4) & 1, c16 = (j & 15) * 8;
        const int bs = s - 8;
        const uint4 v = *reinterpret_cast<const uint4*>(
            &histb[((((bs + st8) & 15)) * 2 + r) * 128 + c16]);
        *reinterpret_cast<uint4*>(
            &Y[((size_t)(bs + st8) * Bb + b0 + r) * Dp + dir * Hh + c16]) = v;
      }
    }
    __syncthreads();
    cur ^= 1;
  }
  {  // final flush (steps 504..511 -> slots 8..15)
    if (tid >= 256) {
      const int j = tid - 256;
      const int st8 = j >> 5, r = (j >> 4) & 1, c16 = (j & 15) * 8;
      const int bs = Tt - 8;
      const uint4 v = *reinterpret_cast<const uint4*>(
          &histb[((((bs + st8) & 15)) * 2 + r) * 128 + c16]);
      *reinterpret_cast<uint4*>(
          &Y[((size_t)(bs + st8) * Bb + b0 + r) * Dp + dir * Hh + c16]) = v;
    }
  }
}

// pot[m][r] = tmp[m][:] . W_a2[r][:]   (tmp fp32)
__global__ __launch_bounds__(256) void pot_k(const float* __restrict__ tmp,
    const float* __restrict__ Wa2, float* __restrict__ pot) {
  const int tid = threadIdx.x;
  const int row = blockIdx.x * 32 + (tid >> 3);
  const int r = tid & 7;
  __shared__ float w2[8 * 129];
  for (int i = tid; i < 1024; i += 256) w2[(i >> 7) * 129 + (i & 127)] = Wa2[i];
  __syncthreads();
  float acc = 0.f;
  const float* tr = tmp + (size_t)row * 128;
#pragma unroll
  for (int k4 = 0; k4 < 32; ++k4) {
    const float4 tv = *reinterpret_cast<const float4*>(tr + k4 * 4);
    acc += tv.x * w2[r * 129 + k4 * 4 + 0];
    acc += tv.y * w2[r * 129 + k4 * 4 + 1];
    acc += tv.z * w2[r * 129 + k4 * 4 + 2];
    acc += tv.w * w2[r * 129 + k4 * 4 + 3];
  }
  pot[(size_t)row * 8 + r] = acc;
}

// masked softmax over t for one (b,r); writes Wt[b][r][t]
__global__ __launch_bounds__(256) void softmax_k(const float* __restrict__ pot,
    const int* __restrict__ length, float* __restrict__ Wt) {
  const int b = blockIdx.x >> 3, r = blockIdx.x & 7;
  const int tid = threadIdx.x;
  const int len = length[b];
  __shared__ float rbuf[4];
  const int t1 = tid, t2 = tid + 256;
  const float x1 = (t1 < len) ? pot[((size_t)t1 * Bb + b) * 8 + r] : -INFINITY;
  const float x2 = (t2 < len) ? pot[((size_t)t2 * Bb + b) * 8 + r] : -INFINITY;
  float m = fmaxf(x1, x2);
#pragma unroll
  for (int off = 32; off >= 1; off >>= 1) m = fmaxf(m, __shfl_xor(m, off));
  if ((tid & 63) == 0) rbuf[tid >> 6] = m;
  __syncthreads();
  m = fmaxf(fmaxf(rbuf[0], rbuf[1]), fmaxf(rbuf[2], rbuf[3]));
  const float e1 = (t1 < len) ? __expf(x1 - m) : 0.f;
  const float e2 = (t2 < len) ? __expf(x2 - m) : 0.f;
  float ssum = e1 + e2;
#pragma unroll
  for (int off = 32; off >= 1; off >>= 1) ssum += __shfl_xor(ssum, off);
  __syncthreads();
  if ((tid & 63) == 0) rbuf[tid >> 6] = ssum;
  __syncthreads();
  ssum = rbuf[0] + rbuf[1] + rbuf[2] + rbuf[3];
  const float inv = 1.0f / ssum;
  float* wrow = Wt + ((size_t)b * 8 + r) * Tt;
  wrow[t1] = e1 * inv;
  wrow[t2] = e2 * inv;
}

// Per-b: pooled = sum_t w[r][t]*Y[t][b][:], logits, log_softmax, gram penalty.
__global__ __launch_bounds__(256) void pool_k(const unsigned short* __restrict__ Y,
    const float* __restrict__ Wt, const float* __restrict__ Wout,
    const float* __restrict__ bout, float* __restrict__ outF,
    float* __restrict__ penpart) {
  const int b = blockIdx.x;
  const int tid = threadIdx.x;
  __shared__ float ws[8 * 513];
  __shared__ float pooled[2048];
  __shared__ float red[256];
  __shared__ float lg[8];
  for (int i = tid; i < 4096; i += 256) ws[(i >> 9) * 513 + (i & 511)] = Wt[(size_t)b * 4096 + i];
  __syncthreads();
  float acc[8] = {};
  for (int t = 0; t < Tt; ++t) {
    const float y = b2f(Y[((size_t)t * Bb + b) * Dp + tid]);
#pragma unroll
    for (int r = 0; r < 8; ++r) acc[r] += ws[r * 513 + t] * y;
  }
#pragma unroll
  for (int r = 0; r < 8; ++r) pooled[r * 256 + tid] = acc[r];
  __syncthreads();
  for (int o = 0; o < 7; ++o) {
    float p = 0.f;
    for (int j = tid; j < 2048; j += 256) p += pooled[j] * Wout[(size_t)o * 2048 + j];
    red[tid] = p;
    __syncthreads();
    for (int st = 128; st >= 1; st >>= 1) {
      if (tid < st) red[tid] += red[tid + st];
      __syncthreads();
    }
    if (tid == 0) lg[o] = red[0] + bout[o];
    __syncthreads();
  }
  if (tid == 0) {
    float mx = lg[0];
    for (int o = 1; o < 7; ++o) mx = fmaxf(mx, lg[o]);
    float ssum = 0.f;
    for (int o = 0; o < 7; ++o) ssum += __expf(lg[o] - mx);
    const float lse = mx + __logf(ssum);
    for (int o = 0; o < 7; ++o) outF[b * 7 + o] = lg[o] - lse;
  }
  for (int i = tid; i < 4096; i += 256) {
    const int rr = i >> 9, t = i & 511;
    ws[rr * 513 + t] = sqrtf(ws[rr * 513 + t]);
  }
  __syncthreads();
  float pp = 0.f;
  if (tid < 64) {
    const int rr = tid >> 3, ssi = tid & 7;
    float g = 0.f;
    for (int t = 0; t < Tt; ++t) g += ws[rr * 513 + t] * ws[ssi * 513 + t];
    const float d = g - 1.0f;
    pp = d * d;
  }
  red[tid] = pp;
  __syncthreads();
  for (int st = 128; st >= 1; st >>= 1) {
    if (tid < st) red[tid] += red[tid + st];
    __syncthreads();
  }
  if (tid == 0) penpart[b] = red[0];
}

__global__ __launch_bounds__(256) void penred_k(const float* __restrict__ penpart,
                                                float* __restrict__ outp) {
  const int tid = threadIdx.x;
  __shared__ float red[256];
  red[tid] = penpart[tid];
  __syncthreads();
  for (int st = 128; st >= 1; st >>= 1) {
    if (tid < st) red[tid] += red[tid + st];
    __syncthreads();
  }
  if (tid == 0) outp[0] = red[0];
}

} // namespace

extern "C" void kernel_launch(void* const* d_in, const int* in_sizes, int n_in,
                              void* d_out, int out_size, void* d_ws, size_t ws_size,
                              hipStream_t stream) {
  (void)in_sizes; (void)n_in; (void)out_size;
  const float* x     = (const float*)d_in[0];
  const float* W_in  = (const float*)d_in[1];
  const float* b_in  = (const float*)d_in[2];
  const float* W_ih  = (const float*)d_in[3];
  const float* b_ih  = (const float*)d_in[4];
  const float* W_hh  = (const float*)d_in[5];
  const float* b_hh  = (const float*)d_in[6];
  const float* wtime = (const float*)d_in[7];
  const float* W_a1  = (const float*)d_in[8];
  const float* b_a1  = (const float*)d_in[9];
  const float* W_a2  = (const float*)d_in[10];
  const float* W_out = (const float*)d_in[11];
  const float* b_out = (const float*)d_in[12];
  const int*   length= (const int*)d_in[13];
  float* outF = (float*)d_out;

  typedef unsigned short bf16;
  char* ws = (char*)d_ws;
  size_t off = 0;
  auto alloc = [&](size_t bytes) {
    void* p = ws + off; off += (bytes + 255) & ~(size_t)255; return p;
  };
  bf16*  act  = (bf16*)alloc((size_t)M * 256 * 2);   // activations [T*B][256], bf16
  bf16*  Pg   = (bf16*)alloc((size_t)M * 512 * 2);   // pre-gates  [T*B][512], bf16
  float* pot  = (float*)alloc((size_t)M * 8 * 4);
  float* Wt   = (float*)alloc((size_t)Bb * 8 * Tt * 4);
  float* penp = (float*)alloc(Bb * 4);
  float* tmpA = (float*)Pg;  // attention tanh activations [M][128] fp32, aliases dead Pg

  if (ws_size < off) return;  // workspace too small: clean absmax-fail, not a crash

  const dim3 blk(256);
  // input layer: rows (t,b) <- x[b][t][:]
  mgemm_k<128, 1, 0, float, bf16><<<dim3(2, M / 128), blk, 0, stream>>>(x, W_in, b_in, nullptr, act, 256);
  // layer 0
  mgemm_k<256, 0, 0, bf16, bf16><<<dim3(4, M / 128), blk, 0, stream>>>(act, W_ih, b_ih, b_hh, Pg, 512);
  lstm_k<<<dim3(256), dim3(512), 0, stream>>>(Pg, W_hh, wtime, act);
  // layer 1 (shared weights)
  mgemm_k<256, 0, 0, bf16, bf16><<<dim3(4, M / 128), blk, 0, stream>>>(act, W_ih, b_ih, b_hh, Pg, 512);
  lstm_k<<<dim3(256), dim3(512), 0, stream>>>(Pg, W_hh, wtime, act);
  // attention
  mgemm_k<256, 0, 1, bf16, float><<<dim3(1, M / 128), blk, 0, stream>>>(act, W_a1, b_a1, nullptr, tmpA, 128);
  pot_k<<<dim3(M / 32), blk, 0, stream>>>(tmpA, W_a2, pot);
  softmax_k<<<dim3(Bb * 8), blk, 0, stream>>>(pot, length, Wt);
  pool_k<<<dim3(Bb), blk, 0, stream>>>(act, Wt, W_out, b_out, outF, penp);
  penred_k<<<dim3(1), blk, 0, stream>>>(penp, outF + Bb * 7);
}